// Round 17
// baseline (311.392 us; speedup 1.0000x reference)
//
#include <hip/hip_runtime.h>
#include <hip/hip_bf16.h>

typedef __hip_bfloat16 bf16;
typedef short short8 __attribute__((ext_vector_type(8)));
typedef float f32x4 __attribute__((ext_vector_type(4)));

#define Lq 512
#define Sm 2048
#define Bb 4
#define Ee 1024
#define Hh 16
#define FFd 2048
#define HDd 64

static __device__ __forceinline__ float b2f(bf16 x) { return __bfloat162float(x); }
static __device__ __forceinline__ bf16 f2b(float x) { return __float2bfloat16(x); }
static __device__ __forceinline__ unsigned short bits(bf16 x) {
    return __builtin_bit_cast(unsigned short, x);
}
static __device__ __forceinline__ float us2f(unsigned short u) {
    return b2f(__builtin_bit_cast(bf16, u));
}

static __device__ __forceinline__ void gload16(const void* g, void* l) {
    __builtin_amdgcn_global_load_lds(
        (const __attribute__((address_space(1))) unsigned int*)g,
        (__attribute__((address_space(3))) unsigned int*)l, 16, 0, 0);
}

static __device__ __forceinline__ short8 pack8(float4 a0, float4 a1) {
    short8 u;
    u[0] = (short)bits(f2b(a0.x)); u[1] = (short)bits(f2b(a0.y));
    u[2] = (short)bits(f2b(a0.z)); u[3] = (short)bits(f2b(a0.w));
    u[4] = (short)bits(f2b(a1.x)); u[5] = (short)bits(f2b(a1.y));
    u[6] = (short)bits(f2b(a1.z)); u[7] = (short)bits(f2b(a1.w));
    return u;
}

// ---------------------------------------------------------------------------
// kc+vc GEMM with fused f32->bf16 B conversion — SCHEDULE FIXED vs R15:
// all next-tile loads (stageA gload_lds + ALL 4 B reg-chunks, 64 VGPR held)
// are issued at the TOP of the iteration; both MFMA halves (~2480 cyc) then
// cover the ~900-cyc HBM latency; ONE vmcnt(0) (near-free) + B ds_writes +
// lgkmcnt(0) + barrier per K-step. R15's two mid-MFMA full drains removed.
// z<4: kc = ckw x bf16(mem+pos) + row-bias; z>=4: vc = cvw x bf16(mem).
// ---------------------------------------------------------------------------
__global__ __launch_bounds__(512, 2)
void kcvc_gemm(const bf16* __restrict__ wk, const bf16* __restrict__ wv,
               const float* __restrict__ mem, const float* __restrict__ pos,
               bf16* __restrict__ kc, bf16* __restrict__ vc,
               const float* __restrict__ kb, const float* __restrict__ vb)
{
    constexpr int BK = 64;
    __shared__ bf16 lA[2][256 * BK];
    __shared__ bf16 lB[2][256 * BK];

    const int tid  = threadIdx.x;
    const int lane = tid & 63;
    const int wm = (tid >> 6) >> 2;
    const int wn = (tid >> 6) & 3;

    int bid = (blockIdx.x & 7) * 32 + (blockIdx.x >> 3);
    const int bx = bid & 3;
    const int by = (bid >> 2) & 7;
    const int z  = bid >> 5;

    const bool isv = z >= 4;
    const int  b   = isv ? z - 4 : z;
    const bf16*  A    = isv ? wv : wk;
    bf16*        C    = (isv ? vc : kc) + (long)b * 2097152;
    const float* bias = isv ? vb : kb;

    const int m0 = bx * 256, n0 = by * 256;
    const bf16*  Abase = A + (long)m0 * 1024;
    const float* Bm = mem + (long)n0 * 4096 + b * 1024;
    const float* Bp = pos + (long)n0 * 4096 + b * 1024;

    const int kgrp = lane >> 4, l16 = lane & 15;
    const int rsw = l16 & 7;

    auto stageA = [&](int buf, int k0) {
#pragma unroll
        for (int r = 0; r < 4; r++) {
            int c = r * 512 + tid;
            int row = c >> 3;
            int ss = (c & 7) ^ (row & 7);
            gload16(Abase + (long)row * 1024 + k0 + ss * 8, &lA[buf][c * 8]);
        }
    };

    // B reg-stage: all 4 chunks/thread per K-step held in registers
    float4 bm[4][2], bq[4][2];
    auto loadB = [&](int k0) {
#pragma unroll
        for (int r = 0; r < 4; r++) {
            int c = r * 512 + tid;
            int row = c >> 3;
            int ss = (c & 7) ^ (row & 7);
            const float* s = Bm + (long)row * 4096 + k0 + ss * 8;
            bm[r][0] = *(const float4*)s;
            bm[r][1] = *(const float4*)(s + 4);
            if (!isv) {
                const float* p = Bp + (long)row * 4096 + k0 + ss * 8;
                bq[r][0] = *(const float4*)p;
                bq[r][1] = *(const float4*)(p + 4);
            }
        }
    };
    auto writeB = [&](int buf) {
#pragma unroll
        for (int r = 0; r < 4; r++) {
            int c = r * 512 + tid;
            float4 a0 = bm[r][0], a1 = bm[r][1];
            if (!isv) {
                a0.x += bq[r][0].x; a0.y += bq[r][0].y;
                a0.z += bq[r][0].z; a0.w += bq[r][0].w;
                a1.x += bq[r][1].x; a1.y += bq[r][1].y;
                a1.z += bq[r][1].z; a1.w += bq[r][1].w;
            }
            *(short8*)&lB[buf][c * 8] = pack8(a0, a1);
        }
    };

    f32x4 acc[8][4];
#pragma unroll
    for (int i = 0; i < 8; i++)
#pragma unroll
        for (int j = 0; j < 4; j++) acc[i][j] = f32x4{0.f, 0.f, 0.f, 0.f};

    // prologue: tile 0 into buf 0
    stageA(0, 0);
    loadB(0);
    asm volatile("s_waitcnt vmcnt(0)" ::: "memory");
    writeB(0);
    asm volatile("s_waitcnt lgkmcnt(0)" ::: "memory");
    __builtin_amdgcn_s_barrier();

    constexpr int NT = 16;
    for (int t = 0; t < NT; t++) {
        const int buf = t & 1;
        const int k1 = (t + 1) * BK;
        if (t + 1 < NT) { stageA(buf ^ 1, k1); loadB(k1); }

        const bf16* la = lA[buf];
        const bf16* lb = lB[buf];
#pragma unroll
        for (int h = 0; h < 2; h++) {
            const int sd = ((h * 4 + kgrp) ^ rsw) * 8;
            short8 af[8], bv[4];
#pragma unroll
            for (int i = 0; i < 8; i++)
                af[i] = *(const short8*)&la[(wm * 128 + i * 16 + l16) * BK + sd];
#pragma unroll
            for (int j = 0; j < 4; j++)
                bv[j] = *(const short8*)&lb[(wn * 64 + j * 16 + l16) * BK + sd];
            __builtin_amdgcn_s_setprio(1);
#pragma unroll
            for (int i = 0; i < 8; i++)
#pragma unroll
                for (int j = 0; j < 4; j++)
                    acc[i][j] = __builtin_amdgcn_mfma_f32_16x16x32_bf16(af[i], bv[j], acc[i][j], 0, 0, 0);
            __builtin_amdgcn_s_setprio(0);
        }

        if (t + 1 < NT) {
            asm volatile("s_waitcnt vmcnt(0)" ::: "memory");
            writeB(buf ^ 1);
        }
        asm volatile("s_waitcnt lgkmcnt(0)" ::: "memory");
        __builtin_amdgcn_s_barrier();
    }

    // epilogue: row bias + paired bf16x2 stores
#pragma unroll
    for (int i = 0; i < 8; i++) {
#pragma unroll
        for (int j = 0; j < 4; j++) {
#pragma unroll
            for (int r = 0; r < 4; r++) {
                int row = m0 + wm * 128 + i * 16 + kgrp * 4 + r;
                int col = n0 + wn * 64 + j * 16 + l16;
                float v = acc[i][j][r] + bias[row];
                float v2 = __shfl_xor(v, 1);
                if (!(l16 & 1)) {
                    unsigned int pk = (unsigned int)bits(f2b(v)) |
                                      ((unsigned int)bits(f2b(v2)) << 16);
                    *(unsigned int*)&C[(long)row * 2048 + col] = pk;
                }
            }
        }
    }
}

// ---------------------------------------------------------------------------
// Fused flash self-attention (unchanged).
// ---------------------------------------------------------------------------
__global__ __launch_bounds__(512, 2)
void flash_attn(const bf16* __restrict__ qk, const bf16* __restrict__ vt,
                bf16* __restrict__ ctx)
{
    __shared__ bf16 lQ[128 * 64];
    __shared__ bf16 lK[2][64 * 64];
    __shared__ bf16 lV[2][64 * 64];
    __shared__ bf16 lP[128 * 64];
    __shared__ float scb[128];

    const int tid  = threadIdx.x;
    const int lane = tid & 63;
    const int wq   = tid >> 6;
    const int kgrp = lane >> 4, l16 = lane & 15;

    const int qt = blockIdx.x & 3;
    const int bh = blockIdx.x >> 2;
    const int b = bh >> 4, h = bh & 15;
    const int L0 = qt * 128;

#pragma unroll
    for (int it = 0; it < 2; it++) {
        int c = it * 512 + tid;
        int rr = c >> 3, sl = c & 7, ss = sl ^ (rr & 7);
        gload16(qk + ((long)(L0 + rr) * 4 + b) * 2048 + h * 64 + ss * 8,
                &lQ[(it * 512 + wq * 64) * 8]);
    }

    auto stageKV = [&](int buf, int st) {
        int rr = tid >> 3, sl = tid & 7, ss = sl ^ (rr & 7);
        gload16(qk + ((long)(st * 64 + rr) * 4 + b) * 2048 + 1024 + h * 64 + ss * 8,
                &lK[buf][(wq * 64) * 8]);
        gload16(vt + ((long)(b * 1024 + h * 64 + rr)) * 512 + st * 64 + ss * 8,
                &lV[buf][(wq * 64) * 8]);
    };

    auto frag = [&](const bf16* base, int row, int kk) {
        return *(const short8*)&base[row * 64 + (((kk * 4 + kgrp) ^ (l16 & 7)) * 8)];
    };

    f32x4 acc_o[4];
#pragma unroll
    for (int j = 0; j < 4; j++) acc_o[j] = f32x4{0.f, 0.f, 0.f, 0.f};
    float m_run = -1e30f, l_run = 0.f;

    stageKV(0, 0);
    asm volatile("s_waitcnt vmcnt(0)" ::: "memory");
    __builtin_amdgcn_s_barrier();

    int buf = 0;
    for (int st = 0; st < 8; st++) {
        if (st < 7) stageKV(buf ^ 1, st + 1);

        f32x4 accs[4];
#pragma unroll
        for (int fm = 0; fm < 4; fm++) accs[fm] = f32x4{0.f, 0.f, 0.f, 0.f};
        __builtin_amdgcn_s_setprio(1);
#pragma unroll
        for (int kk = 0; kk < 2; kk++) {
            short8 bq = frag(lQ, wq * 16 + l16, kk);
#pragma unroll
            for (int fm = 0; fm < 4; fm++) {
                short8 af = frag(lK[buf], fm * 16 + l16, kk);
                accs[fm] = __builtin_amdgcn_mfma_f32_16x16x32_bf16(af, bq, accs[fm], 0, 0, 0);
            }
        }
        __builtin_amdgcn_s_setprio(0);

        float v[4][4], p[4][4];
        float tmax = -1e30f;
#pragma unroll
        for (int fm = 0; fm < 4; fm++)
#pragma unroll
            for (int r = 0; r < 4; r++) {
                v[fm][r] = accs[fm][r] * 0.125f;
                tmax = fmaxf(tmax, v[fm][r]);
            }
        tmax = fmaxf(tmax, __shfl_xor(tmax, 16));
        tmax = fmaxf(tmax, __shfl_xor(tmax, 32));
        float m_new = fmaxf(m_run, tmax);
        float sc = __expf(m_run - m_new);
        float sum = 0.f;
#pragma unroll
        for (int fm = 0; fm < 4; fm++)
#pragma unroll
            for (int r = 0; r < 4; r++) {
                p[fm][r] = __expf(v[fm][r] - m_new);
                sum += p[fm][r];
            }
        sum += __shfl_xor(sum, 16);
        sum += __shfl_xor(sum, 32);
        l_run = l_run * sc + sum;
        m_run = m_new;

        if (!kgrp) scb[wq * 16 + l16] = sc;
        asm volatile("s_waitcnt lgkmcnt(0)" ::: "memory");
        __builtin_amdgcn_sched_barrier(0);
        float sc2[4];
#pragma unroll
        for (int r = 0; r < 4; r++) sc2[r] = scb[wq * 16 + kgrp * 4 + r];
#pragma unroll
        for (int fn = 0; fn < 4; fn++)
#pragma unroll
            for (int r = 0; r < 4; r++) acc_o[fn][r] *= sc2[r];

#pragma unroll
        for (int fm = 0; fm < 4; fm++) {
            int l = wq * 16 + l16;
            int sp = (fm * 2 + (kgrp >> 1)) ^ (l16 & 7);
            uint2 pk;
            pk.x = (unsigned int)bits(f2b(p[fm][0])) | ((unsigned int)bits(f2b(p[fm][1])) << 16);
            pk.y = (unsigned int)bits(f2b(p[fm][2])) | ((unsigned int)bits(f2b(p[fm][3])) << 16);
            *(uint2*)&lP[l * 64 + sp * 8 + (kgrp & 1) * 4] = pk;
        }
        asm volatile("s_waitcnt lgkmcnt(0)" ::: "memory");
        __builtin_amdgcn_sched_barrier(0);

        __builtin_amdgcn_s_setprio(1);
#pragma unroll
        for (int kk = 0; kk < 2; kk++) {
            short8 ap = frag(lP, wq * 16 + l16, kk);
#pragma unroll
            for (int fn = 0; fn < 4; fn++) {
                short8 bvf = frag(lV[buf], fn * 16 + l16, kk);
                acc_o[fn] = __builtin_amdgcn_mfma_f32_16x16x32_bf16(ap, bvf, acc_o[fn], 0, 0, 0);
            }
        }
        __builtin_amdgcn_s_setprio(0);

        asm volatile("s_waitcnt vmcnt(0)" ::: "memory");
        __builtin_amdgcn_s_barrier();
        buf ^= 1;
    }

    if (!kgrp) scb[wq * 16 + l16] = 1.f / l_run;
    asm volatile("s_waitcnt lgkmcnt(0)" ::: "memory");
    __builtin_amdgcn_sched_barrier(0);
    float inv[4];
#pragma unroll
    for (int r = 0; r < 4; r++) inv[r] = scb[wq * 16 + kgrp * 4 + r];
#pragma unroll
    for (int fn = 0; fn < 4; fn++) {
#pragma unroll
        for (int r = 0; r < 4; r++) {
            int lg = L0 + wq * 16 + kgrp * 4 + r;
            int d  = fn * 16 + l16;
            float vv = acc_o[fn][r] * inv[r];
            float v2 = __shfl_xor(vv, 1);
            if (!(l16 & 1)) {
                unsigned int pk = (unsigned int)bits(f2b(vv)) |
                                  ((unsigned int)bits(f2b(v2)) << 16);
                *(unsigned int*)&ctx[((long)lg * 4 + b) * 1024 + h * 64 + d] = pk;
            }
        }
    }
}

// ---------------------------------------------------------------------------
// NT bf16 MFMA GEMM — BK=64 / 2-buffer / h-split (unchanged).
// ---------------------------------------------------------------------------
template<int BM, int BN>
__global__ __launch_bounds__(256)
void gemm_nt(const bf16* __restrict__ A, const bf16* __restrict__ Bw,
             float* __restrict__ Cf, bf16* __restrict__ Cb,
             const float* __restrict__ bias,
             const bf16* __restrict__ A2, const bf16* __restrict__ B2,
             bf16* __restrict__ Cb2, const float* __restrict__ bias2,
             int gx, int gy,
             int K, long lda, long ldb, long ldc,
             long sA1, long sA2, long sB1, long sB2, long sC1, long sC2,
             int zdiv, int zsplit, int nsplit, float alpha, int mode, int mode2)
{
    constexpr int BK = 64;
    constexpr int RA = BM / 32, RB = BN / 32;
    __shared__ bf16 lA[2][BM * BK];
    __shared__ bf16 lB[2][BN * BK];

    const int tid  = threadIdx.x;
    const int lane = tid & 63;
    const int wave = tid >> 6;
    const int wm = wave >> 1, wn = wave & 1;
    constexpr int RM = BM / 2, RN = BN / 2;
    constexpr int FM = RM / 16, FN = RN / 16;

    const int nwg = gridDim.x;
    const int cpx = nwg >> 3;
    int bid = (blockIdx.x & 7) * cpx + (blockIdx.x >> 3);
    const int bx = bid % gx;
    int tmp = bid / gx;
    const int by = tmp % gy;
    const int z  = tmp / gy;

    const int m0 = bx * BM;
    const int n0 = by * BN;

    const bool use2 = (z >= zsplit) || (n0 >= nsplit);
    const int  zz   = (z >= zsplit) ? z - zsplit : z;
    const bf16*  Ap = (use2 && A2)    ? A2    : A;
    const bf16*  Bp = (use2 && B2)    ? B2    : Bw;
    const float* bp = (use2 && bias2) ? bias2 : bias;
    const int    md = use2 ? mode2 : mode;
    bf16*        Co = (use2 && Cb2)   ? Cb2   : Cb;

    const long offA = (long)(zz / zdiv) * sA1 + (long)(zz % zdiv) * sA2;
    const long offB = (long)(zz / zdiv) * sB1 + (long)(zz % zdiv) * sB2;
    const long offC = (long)(zz / zdiv) * sC1 + (long)(zz % zdiv) * sC2;

    const bf16* Abase = Ap + offA + (long)m0 * lda;
    const bf16* Bbase = Bp + offB + (long)n0 * ldb;

    const int kgrp = lane >> 4;
    const int l16  = lane & 15;
    const int rsw  = l16 & 7;

    auto stage = [&](int buf, int k0) {
#pragma unroll
        for (int r = 0; r < RA; r++) {
            int c = r * 256 + tid;
            int row = c >> 3;
            int ss = (c & 7) ^ (row & 7);
            gload16(Abase + (long)row * lda + k0 + ss * 8, &lA[buf][c * 8]);
        }
#pragma unroll
        for (int r = 0; r < RB; r++) {
            int c = r * 256 + tid;
            int row = c >> 3;
            int ss = (c & 7) ^ (row & 7);
            gload16(Bbase + (long)row * ldb + k0 + ss * 8, &lB[buf][c * 8]);
        }
    };

    f32x4 acc[FM][FN];
#pragma unroll
    for (int i = 0; i < FM; i++)
#pragma unroll
        for (int j = 0; j < FN; j++) acc[i][j] = f32x4{0.f, 0.f, 0.f, 0.f};

    const int nt = K / BK;
    stage(0, 0);
    asm volatile("s_waitcnt vmcnt(0)" ::: "memory");
    __builtin_amdgcn_s_barrier();

    for (int t = 0; t < nt; t++) {
        if (t + 1 < nt) stage((t + 1) & 1, (t + 1) * BK);

        const bf16* la = lA[t & 1];
        const bf16* lb = lB[t & 1];
#pragma unroll
        for (int h = 0; h < 2; h++) {
            const int sd = ((h * 4 + kgrp) ^ rsw) * 8;
            short8 af[FM], bv[FN];
#pragma unroll
            for (int i = 0; i < FM; i++)
                af[i] = *(const short8*)&la[(wm * RM + i * 16 + l16) * BK + sd];
#pragma unroll
            for (int j = 0; j < FN; j++)
                bv[j] = *(const short8*)&lb[(wn * RN + j * 16 + l16) * BK + sd];
            __builtin_amdgcn_s_setprio(1);
#pragma unroll
            for (int i = 0; i < FM; i++)
#pragma unroll
                for (int j = 0; j < FN; j++)
                    acc[i][j] = __builtin_amdgcn_mfma_f32_16x16x32_bf16(af[i], bv[j], acc[i][j], 0, 0, 0);
            __builtin_amdgcn_s_setprio(0);
        }

        asm volatile("s_waitcnt vmcnt(0)" ::: "memory");
        __builtin_amdgcn_s_barrier();
    }

#pragma unroll
    for (int i = 0; i < FM; i++) {
#pragma unroll
        for (int j = 0; j < FN; j++) {
#pragma unroll
            for (int r = 0; r < 4; r++) {
                int row = m0 + wm * RM + i * 16 + kgrp * 4 + r;
                int col = n0 + wn * RN + j * 16 + l16;
                float v = alpha * acc[i][j][r] + (bp ? bp[col] : 0.f);
                float v2 = __shfl_xor(v, 1);
                if (md == 0) {
                    if (!(l16 & 1)) {
                        float2 pv = {v, v2};
                        *(float2*)&Cf[offC + (long)row * ldc + col] = pv;
                    }
                } else if (md == 1) {
                    if (!(l16 & 1)) {
                        unsigned int pk = (unsigned int)bits(f2b(v)) |
                                          ((unsigned int)bits(f2b(v2)) << 16);
                        *(unsigned int*)&Co[offC + (long)row * ldc + col] = pk;
                    }
                } else if (md == 2) {
                    if (!(l16 & 1)) {
                        unsigned int pk = (unsigned int)bits(f2b(fmaxf(v, 0.f))) |
                                          ((unsigned int)bits(f2b(fmaxf(v2, 0.f))) << 16);
                        *(unsigned int*)&Co[offC + (long)row * ldc + col] = pk;
                    }
                } else {
                    int o = col - nsplit;
                    Cb2[((long)(row & 3) * 1024 + o) * 512 + (row >> 2)] = f2b(v);
                }
            }
        }
    }
}

// ---------------------------------------------------------------------------
// f32->bf16 convert prepass — 7 segments (mem/pos fused into kcvc).
// ---------------------------------------------------------------------------
struct Cvt2Seg { const float* a; const float* b; bf16* d; bf16* d2; int nblk; };
struct Cvt2Args { Cvt2Seg s[8]; };

__global__ __launch_bounds__(256)
void cvt_kernel(Cvt2Args args)
{
    for (int ci = blockIdx.x; ci < 6144; ci += 2048) {
        int rem = ci;
        int si = 0;
        while (si < 7 && rem >= args.s[si].nblk) { rem -= args.s[si].nblk; si++; }
        Cvt2Seg sg = args.s[si];
        const long i = (long)rem * 2048 + threadIdx.x * 8;

        float4 a0 = *(const float4*)(sg.a + i);
        float4 a1 = *(const float4*)(sg.a + i + 4);
        float4 s0 = a0, s1 = a1;
        if (sg.b) {
            float4 b0 = *(const float4*)(sg.b + i);
            float4 b1 = *(const float4*)(sg.b + i + 4);
            s0.x += b0.x; s0.y += b0.y; s0.z += b0.z; s0.w += b0.w;
            s1.x += b1.x; s1.y += b1.y; s1.z += b1.z; s1.w += b1.w;
        }
        *(short8*)((unsigned short*)sg.d + i) = pack8(s0, s1);
        if (sg.d2) {
            *(short8*)((unsigned short*)sg.d2 + i) = pack8(a0, a1);
        }
    }
}

// ---------------------------------------------------------------------------
// LayerNorm over E=1024: input x (f32) OR xB (bf16); + res (f32) / resb.
// ---------------------------------------------------------------------------
__global__ __launch_bounds__(256)
void ln_kernel(const float* __restrict__ x, const bf16* __restrict__ xB,
               const float* __restrict__ res, const float* __restrict__ resb,
               const float* __restrict__ g, const float* __restrict__ be,
               float* __restrict__ outF, bf16* __restrict__ outB)
{
    long row = blockIdx.x;
    int tid = threadIdx.x, lane = tid & 63, w = tid >> 6;
    float vv[4];
    if (x) {
        float4 xv = *(const float4*)(x + row * 1024 + tid * 4);
        vv[0] = xv.x; vv[1] = xv.y; vv[2] = xv.z; vv[3] = xv.w;
    } else {
        ushort4 xv = *(const ushort4*)((const unsigned short*)xB + row * 1024 + tid * 4);
        vv[0] = us2f(xv.x); vv[1] = us2f(xv.y); vv[2] = us2f(xv.z); vv[3] = us2f(xv.w);
    }
    if (res) {
        float4 rv = *(const float4*)(res + row * 1024 + tid * 4);
        vv[0] += rv.x; vv[1] += rv.y; vv[2] += rv.z; vv[3] += rv.w;
    }
    if (resb) {
        float4 rv = *(const float4*)(resb + (row & 3) * 1024 + tid * 4);
        vv[0] += rv.x; vv[1] += rv.y; vv[2] += rv.z; vv[3] += rv.w;
    }
    float s = vv[0] + vv[1] + vv[2] + vv[3];
    float q = vv[0] * vv[0] + vv[1] * vv[1] + vv[2] * vv[2] + vv[3] * vv[3];
    __shared__ float rs[4], rq[4];
    for (int o = 32; o; o >>= 1) { s += __shfl_xor(s, o); q += __shfl_xor(q, o); }
    if (!lane) { rs[w] = s; rq[w] = q; }
    __syncthreads();
    s = rs[0] + rs[1] + rs[2] + rs[3];
    q = rq[0] + rq[1] + rq[2] + rq[3];
    float mean = s * (1.f / 1024.f);
    float var  = q * (1.f / 1024.f) - mean * mean;
    float rstd = rsqrtf(var + 1e-5f);
    float4 gv = *(const float4*)(g + tid * 4);
    float4 bv = *(const float4*)(be + tid * 4);
    float o0 = (vv[0] - mean) * rstd * gv.x + bv.x;
    float o1 = (vv[1] - mean) * rstd * gv.y + bv.y;
    float o2 = (vv[2] - mean) * rstd * gv.z + bv.z;
    float o3 = (vv[3] - mean) * rstd * gv.w + bv.w;
    if (outF) {
        float4 ov = {o0, o1, o2, o3};
        *(float4*)(outF + row * 1024 + tid * 4) = ov;
    }
    if (outB) {
        ushort4 u;
        u.x = bits(f2b(o0)); u.y = bits(f2b(o1));
        u.z = bits(f2b(o2)); u.w = bits(f2b(o3));
        *reinterpret_cast<ushort4*>((unsigned short*)outB + row * 1024 + tid * 4) = u;
    }
}

// ---------------------------------------------------------------------------
// asum partials over L, then reduce
// ---------------------------------------------------------------------------
__global__ __launch_bounds__(256)
void asum_part_kernel(const float* __restrict__ t1, const float* __restrict__ qp,
                      float* __restrict__ part)
{
    int blk = blockIdx.x;
    int lc = blk >> 4, b = (blk >> 2) & 3, ec = blk & 3;
    int e = ec * 256 + threadIdx.x;
    float acc = 0.f;
#pragma unroll 4
    for (int l = lc * 32; l < lc * 32 + 32; l++) {
        long idx = ((long)(l * 4 + b)) * 1024 + e;
        acc += t1[idx] + qp[idx];
    }
    part[(lc * 4 + b) * 1024 + e] = acc;
}

__global__ __launch_bounds__(256)
void asum_reduce_kernel(const float* __restrict__ part, float* __restrict__ asum)
{
    int b = blockIdx.x >> 2, ec = blockIdx.x & 3;
    int e = ec * 256 + threadIdx.x;
    float acc = 0.f;
#pragma unroll
    for (int lc = 0; lc < 16; lc++) acc += part[(lc * 4 + b) * 1024 + e];
    asum[b * 1024 + e] = acc;
}

// ---------------------------------------------------------------------------
// qsum[b,o] = sum_e cq_w[o,e]*asum[b,e] + 512*cq_b[o]
// ---------------------------------------------------------------------------
__global__ __launch_bounds__(256)
void qsum_kernel(const float* __restrict__ cqw, const float* __restrict__ cqb,
                 const float* __restrict__ asum, float* __restrict__ qsum)
{
    int o = blockIdx.x * 4 + (threadIdx.x >> 6);
    int lane = threadIdx.x & 63;
    float a0 = 0, a1 = 0, a2 = 0, a3 = 0;
    for (int j = 0; j < 16; j++) {
        int e = lane + j * 64;
        float wv = cqw[(long)o * 1024 + e];
        a0 += wv * asum[e];
        a1 += wv * asum[1024 + e];
        a2 += wv * asum[2048 + e];
        a3 += wv * asum[3072 + e];
    }
    for (int t = 32; t; t >>= 1) {
        a0 += __shfl_xor(a0, t); a1 += __shfl_xor(a1, t);
        a2 += __shfl_xor(a2, t); a3 += __shfl_xor(a3, t);
    }
    if (!lane) {
        float bb = 512.f * cqb[o];
        qsum[o] = a0 + bb; qsum[1024 + o] = a1 + bb;
        qsum[2048 + o] = a2 + bb; qsum[3072 + o] = a3 + bb;
    }
}

// ---------------------------------------------------------------------------
// cross stage A: s1[bh][m]
// ---------------------------------------------------------------------------
__global__ __launch_bounds__(256)
void s1_kernel(const bf16* __restrict__ kc, const float* __restrict__ qsum,
               float* __restrict__ s1)
{
    int bh = blockIdx.x, b = bh >> 4, h = bh & 15;
    int m = blockIdx.y * 256 + threadIdx.x;
    __shared__ float qd[64];
    if (threadIdx.x < 64) qd[threadIdx.x] = qsum[b * 1024 + threadIdx.x * 16 + h];
    __syncthreads();
    const bf16* kcb = kc + (long)b * 2048 * 1024 + (long)h * 2048 + m;
    float acc = 0.f;
#pragma unroll 8
    for (int d = 0; d < 64; d++) acc += qd[d] * b2f(kcb[(long)d * 16 * 2048]);
    s1[(long)bh * 2048 + m] = acc * 0.125f;
}

// ---------------------------------------------------------------------------
// cross stage B: per (b,h,n) row max & expsum
// ---------------------------------------------------------------------------
__global__ __launch_bounds__(256)
void bsum_kernel(const bf16* __restrict__ kc, const float* __restrict__ s1,
                 float* __restrict__ rmax, float* __restrict__ rsum)
{
    int bh = blockIdx.x >> 6, n = blockIdx.x & 63;
    int b = bh >> 4, h = bh & 15;
    int tid = threadIdx.x, lane = tid & 63, w = tid >> 6;
    const bf16* row = kc + (long)b * 2048 * 1024 + (long)(n * 16 + h) * 2048;
    const float* s1r = s1 + (long)bh * 2048;
    float t[8];
    float mx = -1e30f;
#pragma unroll
    for (int i = 0; i < 8; i++) {
        int m = tid + i * 256;
        t[i] = b2f(row[m]) * s1r[m];
        mx = fmaxf(mx, t[i]);
    }
    __shared__ float redm[4], reds[4];
    for (int o = 32; o; o >>= 1) mx = fmaxf(mx, __shfl_xor(mx, o));
    if (!lane) redm[w] = mx;
    __syncthreads();
    mx = fmaxf(fmaxf(redm[0], redm[1]), fmaxf(redm[2], redm[3]));
    float s = 0.f;
#pragma unroll
    for (int i = 0; i < 8; i++) s += __expf(t[i] - mx);
    for (int o = 32; o; o >>= 1) s += __shfl_xor(s, o);
    if (!lane) reds[w] = s;
    __syncthreads();
    if (!tid) {
        rmax[bh * 64 + n] = mx;
        rsum[bh * 64 + n] = reds[0] + reds[1] + reds[2] + reds[3];
    }
}

// ---------------------------------------------------------------------------
// cross stage C: wpr[bh][m]
// ---------------------------------------------------------------------------
__global__ __launch_bounds__(256)
void wpr_kernel(const bf16* __restrict__ kc, const float* __restrict__ s1,
                const float* __restrict__ rmax, const float* __restrict__ rsum,
                const float* __restrict__ dw, float* __restrict__ wpr)
{
    int bh = blockIdx.x, b = bh >> 4, h = bh & 15;
    int m = blockIdx.y * 256 + threadIdx.x;
    __shared__ float cf[64], cm[64];
    if (threadIdx.x < 64) {
        cf[threadIdx.x] = dw[threadIdx.x] / rsum[bh * 64 + threadIdx.x];
        cm[threadIdx.x] = rmax[bh * 64 + threadIdx.x];
    }
    __syncthreads();
    float s1v = s1[(long)bh * 2048 + m];
    const bf16* kcb = kc + (long)b * 2048 * 1024 + (long)h * 2048 + m;
    float acc = 0.f;
#pragma unroll 8
    for (int n = 0; n < 64; n++)
        acc += cf[n] * __expf(b2f(kcb[(long)n * 16 * 2048]) * s1v - cm[n]);
    wpr[(long)bh * 2048 + m] = acc;
}

// ---------------------------------------------------------------------------
// cross stage D: outs[b, d*16+h] = sum_m wpr[bh][m]*vc[b, d*16+h, m] + db
// ---------------------------------------------------------------------------
__global__ __launch_bounds__(256)
void cout_kernel(const bf16* __restrict__ vc, const float* __restrict__ wpr,
                 const float* __restrict__ db, float* __restrict__ outs)
{
    int bh = blockIdx.x >> 2, dg = blockIdx.x & 3;
    int b = bh >> 4, h = bh & 15;
    int tid = threadIdx.x, lane = tid & 63, w = tid >> 6;
    __shared__ float lwpr[2048];
#pragma unroll
    for (int i = 0; i < 8; i++) lwpr[tid + i * 256] = wpr[(long)bh * 2048 + tid + i * 256];
    __syncthreads();
#pragma unroll
    for (int dd = 0; dd < 4; dd++) {
        int d = dg * 16 + w * 4 + dd;
        int o = d * 16 + h;
        const bf16* vrow = vc + (long)b * 2048 * 1024 + (long)o * 2048;
        float acc = 0.f;
#pragma unroll
        for (int j = 0; j < 4; j++) {
            int m = j * 512 + lane * 8;
            short8 vv = *(const short8*)&vrow[m];
#pragma unroll
            for (int k = 0; k < 8; k++) {
                bf16 bb = __builtin_bit_cast(bf16, (unsigned short)vv[k]);
                acc += lwpr[m + k] * b2f(bb);
            }
        }
        for (int t2 = 32; t2; t2 >>= 1) acc += __shfl_xor(acc, t2);
        if (!lane) outs[b * 1024 + o] = acc + db[0];
    }
}

// ---------------------------------------------------------------------------
extern "C" void kernel_launch(void* const* d_in, const int* in_sizes, int n_in,
                              void* d_out, int out_size, void* d_ws, size_t ws_size,
                              hipStream_t stream)
{
    const float* tgt  = (const float*)d_in[0];
    const float* mem  = (const float*)d_in[1];
    const float* pos  = (const float*)d_in[2];
    const float* qp   = (const float*)d_in[3];
    const float* ipw  = (const float*)d_in[4];
    const float* ipb  = (const float*)d_in[5];
    const float* outw = (const float*)d_in[6];
    const float* outb = (const float*)d_in[7];
    const float* cqw  = (const float*)d_in[8];
    const float* cqb  = (const float*)d_in[9];
    const float* ckw  = (const float*)d_in[10];
    const float* ckb  = (const float*)d_in[11];
    const float* cvw  = (const float*)d_in[12];
    const float* cvb  = (const float*)d_in[13];
    const float* dww  = (const float*)d_in[14];
    const float* dwb  = (const float*)d_in[15];
    const float* l1w  = (const float*)d_in[16];
    const float* l1b  = (const float*)d_in[17];
    const float* l2w  = (const float*)d_in[18];
    const float* l2b  = (const float*)d_in[19];
    const float* n1g  = (const float*)d_in[20];
    const float* n1b  = (const float*)d_in[21];
    const float* n2g  = (const float*)d_in[22];
    const float* n2b  = (const float*)d_in[23];
    const float* n3g  = (const float*)d_in[24];
    const float* n3b  = (const float*)d_in[25];

    char* ws = (char*)d_ws;
    auto MB = [](long x) { return x << 20; };
    bf16* w_ip    = (bf16*)(ws + MB(0));    // 6 MB
    bf16* w_out   = (bf16*)(ws + MB(6));    // 2 MB
    bf16* w_ck    = (bf16*)(ws + MB(8));    // 2 MB
    bf16* w_cv    = (bf16*)(ws + MB(10));   // 2 MB
    bf16* w_l1    = (bf16*)(ws + MB(12));   // 4 MB
    bf16* w_l2    = (bf16*)(ws + MB(16));   // 4 MB
    bf16* qkin    = (bf16*)(ws + MB(20));   // 4 MB
    bf16* tgtb    = (bf16*)(ws + MB(24));   // 4 MB
    bf16* qkbuf   = (bf16*)(ws + MB(60));   // 8 MB
    bf16* vtb     = (bf16*)(ws + MB(68));   // 4 MB
    bf16* kcb     = (bf16*)(ws + MB(72));   // 16 MB
    bf16* ctxb    = (bf16*)(ws + MB(104));  // 4 MB
    bf16* atmpb   = (bf16*)(ws + MB(108));  // 4 MB (LN1 input, bf16)
    float* s1buf  = (float*)(ws + MB(108)); // 512 KB (reuses slot after LN1)
    float* wprbuf = (float*)(ws + MB(109)); // 512 KB
    float* rmax   = (float*)(ws + MB(110));              // 16 KB
    float* rsum   = (float*)(ws + MB(110) + (64 << 10)); // 16 KB
    float* part   = (float*)(ws + MB(111)); // 256 KB
    float* tgt1   = (float*)(ws + MB(116)); // 8 MB
    float* asum   = (float*)(ws + MB(124)); // 16 KB
    float* qsum   = (float*)(ws + MB(125)); // 16 KB
    bf16* vcb     = (bf16*)(ws + MB(126));  // 16 MB
    float* outs   = (float*)(ws + MB(142)); // 16 KB
    float* tgt2   = (float*)(ws + MB(143)); // 8 MB
    bf16* tgt2b   = (bf16*)(ws + MB(151));  // 4 MB
    bf16* ff1b    = (bf16*)(ws + MB(155));  // 8 MB
    bf16* ff2b    = (bf16*)(ws + MB(163));  // 4 MB

    const int BIGZ = 1000000, BIGN = 1 << 30;

    // --- prepass: weights + tgt conversions only (mem/pos fused into kcvc) ---
    Cvt2Args ca{};
    ca.s[0] = {ipw,  nullptr, w_ip,    nullptr, 1536};
    ca.s[1] = {outw, nullptr, w_out,   nullptr, 512};
    ca.s[2] = {ckw,  nullptr, w_ck,    nullptr, 512};
    ca.s[3] = {cvw,  nullptr, w_cv,    nullptr, 512};
    ca.s[4] = {l1w,  nullptr, w_l1,    nullptr, 1024};
    ca.s[5] = {l2w,  nullptr, w_l2,    nullptr, 1024};
    ca.s[6] = {tgt,  qp,      qkin,    tgtb,    1024};
    cvt_kernel<<<dim3(2048, 1, 1), 256, 0, stream>>>(ca);

    // --- fused qkv projection: [2048,1024]x[1024,3072] (768 blocks) ---
    gemm_nt<64, 128><<<dim3(768, 1, 1), 256, 0, stream>>>(
        qkin, w_ip, nullptr, qkbuf, ipb,
        tgtb, nullptr, vtb, nullptr,
        32, 24,
        1024, 1024, 1024, 2048,
        0, 0, 0, 0, 0, 0, 1, BIGZ, 2048, 1.f, 1, 3);

    // --- fused flash self-attention ---
    flash_attn<<<dim3(256, 1, 1), 512, 0, stream>>>(qkbuf, vtb, ctxb);

    // --- out projection -> atmpb bf16 ---
    gemm_nt<64, 128><<<dim3(256, 1, 1), 256, 0, stream>>>(
        ctxb, w_out, nullptr, atmpb, outb,
        nullptr, nullptr, nullptr, nullptr,
        32, 8,
        1024, 1024, 1024, 1024,
        0, 0, 0, 0, 0, 0, 1, BIGZ, BIGN, 1.f, 1, 1);

    // --- LN1: tgt1 = LN(bf16(atmp) + tgt) ---
    ln_kernel<<<dim3(2048, 1, 1), 256, 0, stream>>>(
        nullptr, atmpb, tgt, nullptr, n1g, n1b, tgt1, nullptr);

    // --- qc path ---
    asum_part_kernel<<<dim3(256, 1, 1), 256, 0, stream>>>(tgt1, qp, part);
    asum_reduce_kernel<<<dim3(16, 1, 1), 256, 0, stream>>>(part, asum);
    qsum_kernel<<<dim3(256, 1, 1), 256, 0, stream>>>(cqw, cqb, asum, qsum);

    // --- fused kc+vc with inline mem/pos conversion (256 blocks x 512 thr) ---
    kcvc_gemm<<<dim3(256, 1, 1), 512, 0, stream>>>(
        w_ck, w_cv, mem, pos, kcb, vcb, ckb, cvb);

    // --- cross attention stages ---
    s1_kernel<<<dim3(64, 8, 1), 256, 0, stream>>>(kcb, qsum, s1buf);
    bsum_kernel<<<dim3(4096, 1, 1), 256, 0, stream>>>(kcb, s1buf, rmax, rsum);
    wpr_kernel<<<dim3(64, 8, 1), 256, 0, stream>>>(kcb, s1buf, rmax, rsum, dww, wprbuf);
    cout_kernel<<<dim3(256, 1, 1), 256, 0, stream>>>(vcb, wprbuf, dwb, outs);

    // --- LN2 ---
    ln_kernel<<<dim3(2048, 1, 1), 256, 0, stream>>>(
        tgt1, nullptr, nullptr, outs, n2g, n2b, tgt2, tgt2b);

    // --- FFN ---
    gemm_nt<64, 128><<<dim3(512, 1, 1), 256, 0, stream>>>(
        tgt2b, w_l1, nullptr, ff1b, l1b,
        nullptr, nullptr, nullptr, nullptr,
        32, 16,
        1024, 1024, 1024, 2048,
        0, 0, 0, 0, 0, 0, 1, BIGZ, BIGN, 1.f, 2, 2);

    gemm_nt<64, 128><<<dim3(256, 1, 1), 256, 0, stream>>>(
        ff1b, w_l2, nullptr, ff2b, l2b,
        nullptr, nullptr, nullptr, nullptr,
        32, 8,
        2048, 2048, 2048, 1024,
        0, 0, 0, 0, 0, 0, 1, BIGZ, BIGN, 1.f, 1, 1);

    // --- LN3 -> d_out ---
    ln_kernel<<<dim3(2048, 1, 1), 256, 0, stream>>>(
        nullptr, ff2b, tgt2, nullptr, n3g, n3b, (float*)d_out, nullptr);
}

// Round 18
// 258.840 us; speedup vs baseline: 1.2030x; 1.2030x over previous
//
#include <hip/hip_runtime.h>
#include <hip/hip_bf16.h>

typedef __hip_bfloat16 bf16;
typedef short short8 __attribute__((ext_vector_type(8)));
typedef float f32x4 __attribute__((ext_vector_type(4)));

#define Lq 512
#define Sm 2048
#define Bb 4
#define Ee 1024
#define Hh 16
#define FFd 2048
#define HDd 64

static __device__ __forceinline__ float b2f(bf16 x) { return __bfloat162float(x); }
static __device__ __forceinline__ bf16 f2b(float x) { return __float2bfloat16(x); }
static __device__ __forceinline__ unsigned short bits(bf16 x) {
    return __builtin_bit_cast(unsigned short, x);
}
static __device__ __forceinline__ float us2f(unsigned short u) {
    return b2f(__builtin_bit_cast(bf16, u));
}

static __device__ __forceinline__ void gload16(const void* g, void* l) {
    __builtin_amdgcn_global_load_lds(
        (const __attribute__((address_space(1))) unsigned int*)g,
        (__attribute__((address_space(3))) unsigned int*)l, 16, 0, 0);
}

static __device__ __forceinline__ short8 pack8(float4 a0, float4 a1) {
    short8 u;
    u[0] = (short)bits(f2b(a0.x)); u[1] = (short)bits(f2b(a0.y));
    u[2] = (short)bits(f2b(a0.z)); u[3] = (short)bits(f2b(a0.w));
    u[4] = (short)bits(f2b(a1.x)); u[5] = (short)bits(f2b(a1.y));
    u[6] = (short)bits(f2b(a1.z)); u[7] = (short)bits(f2b(a1.w));
    return u;
}

// ---------------------------------------------------------------------------
// kc+vc GEMM, 256x256 tile, BK=64, 2 LDS buffers (R13/R14 configuration —
// pure global_load_lds staging; fusion experiments R15/R16 reverted: both
// regressed via mid-MFMA drains (+27us) then register spills (+77us)).
// z<4: kc = ckw x memposb + row-bias; z>=4: vc = cvw x memb + row-bias.
// ---------------------------------------------------------------------------
__global__ __launch_bounds__(512, 2)
void kcvc_gemm(const bf16* __restrict__ wk, const bf16* __restrict__ wv,
               const bf16* __restrict__ mp, const bf16* __restrict__ mo,
               bf16* __restrict__ kc, bf16* __restrict__ vc,
               const float* __restrict__ kb, const float* __restrict__ vb)
{
    constexpr int BK = 64;
    __shared__ bf16 lA[2][256 * BK];
    __shared__ bf16 lB[2][256 * BK];

    const int tid  = threadIdx.x;
    const int lane = tid & 63;
    const int wm = (tid >> 6) >> 2;
    const int wn = (tid >> 6) & 3;

    int bid = (blockIdx.x & 7) * 32 + (blockIdx.x >> 3);
    const int bx = bid & 3;
    const int by = (bid >> 2) & 7;
    const int z  = bid >> 5;

    const bool isv = z >= 4;
    const int  b   = isv ? z - 4 : z;
    const bf16*  A    = isv ? wv : wk;
    const bf16*  B    = (isv ? mo : mp) + b * 1024;
    bf16*        C    = (isv ? vc : kc) + (long)b * 2097152;
    const float* bias = isv ? vb : kb;

    const int m0 = bx * 256, n0 = by * 256;
    const bf16* Abase = A + (long)m0 * 1024;
    const bf16* Bbase = B + (long)n0 * 4096;

    const int kgrp = lane >> 4, l16 = lane & 15;
    const int rsw = l16 & 7;

    auto stage = [&](int buf, int k0) {
#pragma unroll
        for (int r = 0; r < 4; r++) {
            int c = r * 512 + tid;
            int row = c >> 3;
            int ss = (c & 7) ^ (row & 7);
            gload16(Abase + (long)row * 1024 + k0 + ss * 8, &lA[buf][c * 8]);
        }
#pragma unroll
        for (int r = 0; r < 4; r++) {
            int c = r * 512 + tid;
            int row = c >> 3;
            int ss = (c & 7) ^ (row & 7);
            gload16(Bbase + (long)row * 4096 + k0 + ss * 8, &lB[buf][c * 8]);
        }
    };

    f32x4 acc[8][4];
#pragma unroll
    for (int i = 0; i < 8; i++)
#pragma unroll
        for (int j = 0; j < 4; j++) acc[i][j] = f32x4{0.f, 0.f, 0.f, 0.f};

    stage(0, 0);
    asm volatile("s_waitcnt vmcnt(0)" ::: "memory");
    __builtin_amdgcn_s_barrier();

    constexpr int NT = 16;
    for (int t = 0; t < NT; t++) {
        if (t + 1 < NT) stage((t + 1) & 1, (t + 1) * BK);

        const bf16* la = lA[t & 1];
        const bf16* lb = lB[t & 1];
#pragma unroll
        for (int h = 0; h < 2; h++) {
            const int sd = ((h * 4 + kgrp) ^ rsw) * 8;
            short8 af[8], bv[4];
#pragma unroll
            for (int i = 0; i < 8; i++)
                af[i] = *(const short8*)&la[(wm * 128 + i * 16 + l16) * BK + sd];
#pragma unroll
            for (int j = 0; j < 4; j++)
                bv[j] = *(const short8*)&lb[(wn * 64 + j * 16 + l16) * BK + sd];
            __builtin_amdgcn_s_setprio(1);
#pragma unroll
            for (int i = 0; i < 8; i++)
#pragma unroll
                for (int j = 0; j < 4; j++)
                    acc[i][j] = __builtin_amdgcn_mfma_f32_16x16x32_bf16(af[i], bv[j], acc[i][j], 0, 0, 0);
            __builtin_amdgcn_s_setprio(0);
        }

        asm volatile("s_waitcnt vmcnt(0)" ::: "memory");
        __builtin_amdgcn_s_barrier();
    }

#pragma unroll
    for (int i = 0; i < 8; i++) {
#pragma unroll
        for (int j = 0; j < 4; j++) {
#pragma unroll
            for (int r = 0; r < 4; r++) {
                int row = m0 + wm * 128 + i * 16 + kgrp * 4 + r;
                int col = n0 + wn * 64 + j * 16 + l16;
                float v = acc[i][j][r] + bias[row];
                float v2 = __shfl_xor(v, 1);
                if (!(l16 & 1)) {
                    unsigned int pk = (unsigned int)bits(f2b(v)) |
                                      ((unsigned int)bits(f2b(v2)) << 16);
                    *(unsigned int*)&C[(long)row * 2048 + col] = pk;
                }
            }
        }
    }
}

// ---------------------------------------------------------------------------
// Fused flash self-attention (unchanged).
// ---------------------------------------------------------------------------
__global__ __launch_bounds__(512, 2)
void flash_attn(const bf16* __restrict__ qk, const bf16* __restrict__ vt,
                bf16* __restrict__ ctx)
{
    __shared__ bf16 lQ[128 * 64];
    __shared__ bf16 lK[2][64 * 64];
    __shared__ bf16 lV[2][64 * 64];
    __shared__ bf16 lP[128 * 64];
    __shared__ float scb[128];

    const int tid  = threadIdx.x;
    const int lane = tid & 63;
    const int wq   = tid >> 6;
    const int kgrp = lane >> 4, l16 = lane & 15;

    const int qt = blockIdx.x & 3;
    const int bh = blockIdx.x >> 2;
    const int b = bh >> 4, h = bh & 15;
    const int L0 = qt * 128;

#pragma unroll
    for (int it = 0; it < 2; it++) {
        int c = it * 512 + tid;
        int rr = c >> 3, sl = c & 7, ss = sl ^ (rr & 7);
        gload16(qk + ((long)(L0 + rr) * 4 + b) * 2048 + h * 64 + ss * 8,
                &lQ[(it * 512 + wq * 64) * 8]);
    }

    auto stageKV = [&](int buf, int st) {
        int rr = tid >> 3, sl = tid & 7, ss = sl ^ (rr & 7);
        gload16(qk + ((long)(st * 64 + rr) * 4 + b) * 2048 + 1024 + h * 64 + ss * 8,
                &lK[buf][(wq * 64) * 8]);
        gload16(vt + ((long)(b * 1024 + h * 64 + rr)) * 512 + st * 64 + ss * 8,
                &lV[buf][(wq * 64) * 8]);
    };

    auto frag = [&](const bf16* base, int row, int kk) {
        return *(const short8*)&base[row * 64 + (((kk * 4 + kgrp) ^ (l16 & 7)) * 8)];
    };

    f32x4 acc_o[4];
#pragma unroll
    for (int j = 0; j < 4; j++) acc_o[j] = f32x4{0.f, 0.f, 0.f, 0.f};
    float m_run = -1e30f, l_run = 0.f;

    stageKV(0, 0);
    asm volatile("s_waitcnt vmcnt(0)" ::: "memory");
    __builtin_amdgcn_s_barrier();

    int buf = 0;
    for (int st = 0; st < 8; st++) {
        if (st < 7) stageKV(buf ^ 1, st + 1);

        f32x4 accs[4];
#pragma unroll
        for (int fm = 0; fm < 4; fm++) accs[fm] = f32x4{0.f, 0.f, 0.f, 0.f};
        __builtin_amdgcn_s_setprio(1);
#pragma unroll
        for (int kk = 0; kk < 2; kk++) {
            short8 bq = frag(lQ, wq * 16 + l16, kk);
#pragma unroll
            for (int fm = 0; fm < 4; fm++) {
                short8 af = frag(lK[buf], fm * 16 + l16, kk);
                accs[fm] = __builtin_amdgcn_mfma_f32_16x16x32_bf16(af, bq, accs[fm], 0, 0, 0);
            }
        }
        __builtin_amdgcn_s_setprio(0);

        float v[4][4], p[4][4];
        float tmax = -1e30f;
#pragma unroll
        for (int fm = 0; fm < 4; fm++)
#pragma unroll
            for (int r = 0; r < 4; r++) {
                v[fm][r] = accs[fm][r] * 0.125f;
                tmax = fmaxf(tmax, v[fm][r]);
            }
        tmax = fmaxf(tmax, __shfl_xor(tmax, 16));
        tmax = fmaxf(tmax, __shfl_xor(tmax, 32));
        float m_new = fmaxf(m_run, tmax);
        float sc = __expf(m_run - m_new);
        float sum = 0.f;
#pragma unroll
        for (int fm = 0; fm < 4; fm++)
#pragma unroll
            for (int r = 0; r < 4; r++) {
                p[fm][r] = __expf(v[fm][r] - m_new);
                sum += p[fm][r];
            }
        sum += __shfl_xor(sum, 16);
        sum += __shfl_xor(sum, 32);
        l_run = l_run * sc + sum;
        m_run = m_new;

        if (!kgrp) scb[wq * 16 + l16] = sc;
        asm volatile("s_waitcnt lgkmcnt(0)" ::: "memory");
        __builtin_amdgcn_sched_barrier(0);
        float sc2[4];
#pragma unroll
        for (int r = 0; r < 4; r++) sc2[r] = scb[wq * 16 + kgrp * 4 + r];
#pragma unroll
        for (int fn = 0; fn < 4; fn++)
#pragma unroll
            for (int r = 0; r < 4; r++) acc_o[fn][r] *= sc2[r];

#pragma unroll
        for (int fm = 0; fm < 4; fm++) {
            int l = wq * 16 + l16;
            int sp = (fm * 2 + (kgrp >> 1)) ^ (l16 & 7);
            uint2 pk;
            pk.x = (unsigned int)bits(f2b(p[fm][0])) | ((unsigned int)bits(f2b(p[fm][1])) << 16);
            pk.y = (unsigned int)bits(f2b(p[fm][2])) | ((unsigned int)bits(f2b(p[fm][3])) << 16);
            *(uint2*)&lP[l * 64 + sp * 8 + (kgrp & 1) * 4] = pk;
        }
        asm volatile("s_waitcnt lgkmcnt(0)" ::: "memory");
        __builtin_amdgcn_sched_barrier(0);

        __builtin_amdgcn_s_setprio(1);
#pragma unroll
        for (int kk = 0; kk < 2; kk++) {
            short8 ap = frag(lP, wq * 16 + l16, kk);
#pragma unroll
            for (int fn = 0; fn < 4; fn++) {
                short8 bvf = frag(lV[buf], fn * 16 + l16, kk);
                acc_o[fn] = __builtin_amdgcn_mfma_f32_16x16x32_bf16(ap, bvf, acc_o[fn], 0, 0, 0);
            }
        }
        __builtin_amdgcn_s_setprio(0);

        asm volatile("s_waitcnt vmcnt(0)" ::: "memory");
        __builtin_amdgcn_s_barrier();
        buf ^= 1;
    }

    if (!kgrp) scb[wq * 16 + l16] = 1.f / l_run;
    asm volatile("s_waitcnt lgkmcnt(0)" ::: "memory");
    __builtin_amdgcn_sched_barrier(0);
    float inv[4];
#pragma unroll
    for (int r = 0; r < 4; r++) inv[r] = scb[wq * 16 + kgrp * 4 + r];
#pragma unroll
    for (int fn = 0; fn < 4; fn++) {
#pragma unroll
        for (int r = 0; r < 4; r++) {
            int lg = L0 + wq * 16 + kgrp * 4 + r;
            int d  = fn * 16 + l16;
            float vv = acc_o[fn][r] * inv[r];
            float v2 = __shfl_xor(vv, 1);
            if (!(l16 & 1)) {
                unsigned int pk = (unsigned int)bits(f2b(vv)) |
                                  ((unsigned int)bits(f2b(v2)) << 16);
                *(unsigned int*)&ctx[((long)lg * 4 + b) * 1024 + h * 64 + d] = pk;
            }
        }
    }
}

// ---------------------------------------------------------------------------
// NT bf16 MFMA GEMM — BK=64 / 2-buffer / h-split (unchanged from R14).
// ---------------------------------------------------------------------------
template<int BM, int BN>
__global__ __launch_bounds__(256)
void gemm_nt(const bf16* __restrict__ A, const bf16* __restrict__ Bw,
             float* __restrict__ Cf, bf16* __restrict__ Cb,
             const float* __restrict__ bias,
             const bf16* __restrict__ A2, const bf16* __restrict__ B2,
             bf16* __restrict__ Cb2, const float* __restrict__ bias2,
             int gx, int gy,
             int K, long lda, long ldb, long ldc,
             long sA1, long sA2, long sB1, long sB2, long sC1, long sC2,
             int zdiv, int zsplit, int nsplit, float alpha, int mode, int mode2)
{
    constexpr int BK = 64;
    constexpr int RA = BM / 32, RB = BN / 32;
    __shared__ bf16 lA[2][BM * BK];
    __shared__ bf16 lB[2][BN * BK];

    const int tid  = threadIdx.x;
    const int lane = tid & 63;
    const int wave = tid >> 6;
    const int wm = wave >> 1, wn = wave & 1;
    constexpr int RM = BM / 2, RN = BN / 2;
    constexpr int FM = RM / 16, FN = RN / 16;

    const int nwg = gridDim.x;
    const int cpx = nwg >> 3;
    int bid = (blockIdx.x & 7) * cpx + (blockIdx.x >> 3);
    const int bx = bid % gx;
    int tmp = bid / gx;
    const int by = tmp % gy;
    const int z  = tmp / gy;

    const int m0 = bx * BM;
    const int n0 = by * BN;

    const bool use2 = (z >= zsplit) || (n0 >= nsplit);
    const int  zz   = (z >= zsplit) ? z - zsplit : z;
    const bf16*  Ap = (use2 && A2)    ? A2    : A;
    const bf16*  Bp = (use2 && B2)    ? B2    : Bw;
    const float* bp = (use2 && bias2) ? bias2 : bias;
    const int    md = use2 ? mode2 : mode;
    bf16*        Co = (use2 && Cb2)   ? Cb2   : Cb;

    const long offA = (long)(zz / zdiv) * sA1 + (long)(zz % zdiv) * sA2;
    const long offB = (long)(zz / zdiv) * sB1 + (long)(zz % zdiv) * sB2;
    const long offC = (long)(zz / zdiv) * sC1 + (long)(zz % zdiv) * sC2;

    const bf16* Abase = Ap + offA + (long)m0 * lda;
    const bf16* Bbase = Bp + offB + (long)n0 * ldb;

    const int kgrp = lane >> 4;
    const int l16  = lane & 15;
    const int rsw  = l16 & 7;

    auto stage = [&](int buf, int k0) {
#pragma unroll
        for (int r = 0; r < RA; r++) {
            int c = r * 256 + tid;
            int row = c >> 3;
            int ss = (c & 7) ^ (row & 7);
            gload16(Abase + (long)row * lda + k0 + ss * 8, &lA[buf][c * 8]);
        }
#pragma unroll
        for (int r = 0; r < RB; r++) {
            int c = r * 256 + tid;
            int row = c >> 3;
            int ss = (c & 7) ^ (row & 7);
            gload16(Bbase + (long)row * ldb + k0 + ss * 8, &lB[buf][c * 8]);
        }
    };

    f32x4 acc[FM][FN];
#pragma unroll
    for (int i = 0; i < FM; i++)
#pragma unroll
        for (int j = 0; j < FN; j++) acc[i][j] = f32x4{0.f, 0.f, 0.f, 0.f};

    const int nt = K / BK;
    stage(0, 0);
    asm volatile("s_waitcnt vmcnt(0)" ::: "memory");
    __builtin_amdgcn_s_barrier();

    for (int t = 0; t < nt; t++) {
        if (t + 1 < nt) stage((t + 1) & 1, (t + 1) * BK);

        const bf16* la = lA[t & 1];
        const bf16* lb = lB[t & 1];
#pragma unroll
        for (int h = 0; h < 2; h++) {
            const int sd = ((h * 4 + kgrp) ^ rsw) * 8;
            short8 af[FM], bv[FN];
#pragma unroll
            for (int i = 0; i < FM; i++)
                af[i] = *(const short8*)&la[(wm * RM + i * 16 + l16) * BK + sd];
#pragma unroll
            for (int j = 0; j < FN; j++)
                bv[j] = *(const short8*)&lb[(wn * RN + j * 16 + l16) * BK + sd];
            __builtin_amdgcn_s_setprio(1);
#pragma unroll
            for (int i = 0; i < FM; i++)
#pragma unroll
                for (int j = 0; j < FN; j++)
                    acc[i][j] = __builtin_amdgcn_mfma_f32_16x16x32_bf16(af[i], bv[j], acc[i][j], 0, 0, 0);
            __builtin_amdgcn_s_setprio(0);
        }

        asm volatile("s_waitcnt vmcnt(0)" ::: "memory");
        __builtin_amdgcn_s_barrier();
    }

#pragma unroll
    for (int i = 0; i < FM; i++) {
#pragma unroll
        for (int j = 0; j < FN; j++) {
#pragma unroll
            for (int r = 0; r < 4; r++) {
                int row = m0 + wm * RM + i * 16 + kgrp * 4 + r;
                int col = n0 + wn * RN + j * 16 + l16;
                float v = alpha * acc[i][j][r] + (bp ? bp[col] : 0.f);
                float v2 = __shfl_xor(v, 1);
                if (md == 0) {
                    if (!(l16 & 1)) {
                        float2 pv = {v, v2};
                        *(float2*)&Cf[offC + (long)row * ldc + col] = pv;
                    }
                } else if (md == 1) {
                    if (!(l16 & 1)) {
                        unsigned int pk = (unsigned int)bits(f2b(v)) |
                                          ((unsigned int)bits(f2b(v2)) << 16);
                        *(unsigned int*)&Co[offC + (long)row * ldc + col] = pk;
                    }
                } else if (md == 2) {
                    if (!(l16 & 1)) {
                        unsigned int pk = (unsigned int)bits(f2b(fmaxf(v, 0.f))) |
                                          ((unsigned int)bits(f2b(fmaxf(v2, 0.f))) << 16);
                        *(unsigned int*)&Co[offC + (long)row * ldc + col] = pk;
                    }
                } else {
                    int o = col - nsplit;
                    Cb2[((long)(row & 3) * 1024 + o) * 512 + (row >> 2)] = f2b(v);
                }
            }
        }
    }
}

// ---------------------------------------------------------------------------
// f32->bf16 convert prepass — full 8 segments (R14 configuration).
// ---------------------------------------------------------------------------
struct Cvt2Seg { const float* a; const float* b; bf16* d; bf16* d2; int nblk; };
struct Cvt2Args { Cvt2Seg s[8]; };

__global__ __launch_bounds__(256)
void cvt_kernel(Cvt2Args args)
{
    for (int ci = blockIdx.x; ci < 10240; ci += 2048) {
        int rem = ci;
        int si = 0;
        while (si < 7 && rem >= args.s[si].nblk) { rem -= args.s[si].nblk; si++; }
        Cvt2Seg sg = args.s[si];
        const long i = (long)rem * 2048 + threadIdx.x * 8;

        float4 a0 = *(const float4*)(sg.a + i);
        float4 a1 = *(const float4*)(sg.a + i + 4);
        float4 s0 = a0, s1 = a1;
        if (sg.b) {
            float4 b0 = *(const float4*)(sg.b + i);
            float4 b1 = *(const float4*)(sg.b + i + 4);
            s0.x += b0.x; s0.y += b0.y; s0.z += b0.z; s0.w += b0.w;
            s1.x += b1.x; s1.y += b1.y; s1.z += b1.z; s1.w += b1.w;
        }
        *(short8*)((unsigned short*)sg.d + i) = pack8(s0, s1);
        if (sg.d2) {
            *(short8*)((unsigned short*)sg.d2 + i) = pack8(a0, a1);
        }
    }
}

// ---------------------------------------------------------------------------
// LayerNorm over E=1024: input x (f32) OR xB (bf16); + res (f32) / resb.
// ---------------------------------------------------------------------------
__global__ __launch_bounds__(256)
void ln_kernel(const float* __restrict__ x, const bf16* __restrict__ xB,
               const float* __restrict__ res, const float* __restrict__ resb,
               const float* __restrict__ g, const float* __restrict__ be,
               float* __restrict__ outF, bf16* __restrict__ outB)
{
    long row = blockIdx.x;
    int tid = threadIdx.x, lane = tid & 63, w = tid >> 6;
    float vv[4];
    if (x) {
        float4 xv = *(const float4*)(x + row * 1024 + tid * 4);
        vv[0] = xv.x; vv[1] = xv.y; vv[2] = xv.z; vv[3] = xv.w;
    } else {
        ushort4 xv = *(const ushort4*)((const unsigned short*)xB + row * 1024 + tid * 4);
        vv[0] = us2f(xv.x); vv[1] = us2f(xv.y); vv[2] = us2f(xv.z); vv[3] = us2f(xv.w);
    }
    if (res) {
        float4 rv = *(const float4*)(res + row * 1024 + tid * 4);
        vv[0] += rv.x; vv[1] += rv.y; vv[2] += rv.z; vv[3] += rv.w;
    }
    if (resb) {
        float4 rv = *(const float4*)(resb + (row & 3) * 1024 + tid * 4);
        vv[0] += rv.x; vv[1] += rv.y; vv[2] += rv.z; vv[3] += rv.w;
    }
    float s = vv[0] + vv[1] + vv[2] + vv[3];
    float q = vv[0] * vv[0] + vv[1] * vv[1] + vv[2] * vv[2] + vv[3] * vv[3];
    __shared__ float rs[4], rq[4];
    for (int o = 32; o; o >>= 1) { s += __shfl_xor(s, o); q += __shfl_xor(q, o); }
    if (!lane) { rs[w] = s; rq[w] = q; }
    __syncthreads();
    s = rs[0] + rs[1] + rs[2] + rs[3];
    q = rq[0] + rq[1] + rq[2] + rq[3];
    float mean = s * (1.f / 1024.f);
    float var  = q * (1.f / 1024.f) - mean * mean;
    float rstd = rsqrtf(var + 1e-5f);
    float4 gv = *(const float4*)(g + tid * 4);
    float4 bv = *(const float4*)(be + tid * 4);
    float o0 = (vv[0] - mean) * rstd * gv.x + bv.x;
    float o1 = (vv[1] - mean) * rstd * gv.y + bv.y;
    float o2 = (vv[2] - mean) * rstd * gv.z + bv.z;
    float o3 = (vv[3] - mean) * rstd * gv.w + bv.w;
    if (outF) {
        float4 ov = {o0, o1, o2, o3};
        *(float4*)(outF + row * 1024 + tid * 4) = ov;
    }
    if (outB) {
        ushort4 u;
        u.x = bits(f2b(o0)); u.y = bits(f2b(o1));
        u.z = bits(f2b(o2)); u.w = bits(f2b(o3));
        *reinterpret_cast<ushort4*>((unsigned short*)outB + row * 1024 + tid * 4) = u;
    }
}

// ---------------------------------------------------------------------------
// asum partials over L, then reduce
// ---------------------------------------------------------------------------
__global__ __launch_bounds__(256)
void asum_part_kernel(const float* __restrict__ t1, const float* __restrict__ qp,
                      float* __restrict__ part)
{
    int blk = blockIdx.x;
    int lc = blk >> 4, b = (blk >> 2) & 3, ec = blk & 3;
    int e = ec * 256 + threadIdx.x;
    float acc = 0.f;
#pragma unroll 4
    for (int l = lc * 32; l < lc * 32 + 32; l++) {
        long idx = ((long)(l * 4 + b)) * 1024 + e;
        acc += t1[idx] + qp[idx];
    }
    part[(lc * 4 + b) * 1024 + e] = acc;
}

__global__ __launch_bounds__(256)
void asum_reduce_kernel(const float* __restrict__ part, float* __restrict__ asum)
{
    int b = blockIdx.x >> 2, ec = blockIdx.x & 3;
    int e = ec * 256 + threadIdx.x;
    float acc = 0.f;
#pragma unroll
    for (int lc = 0; lc < 16; lc++) acc += part[(lc * 4 + b) * 1024 + e];
    asum[b * 1024 + e] = acc;
}

// ---------------------------------------------------------------------------
// qsum[b,o] = sum_e cq_w[o,e]*asum[b,e] + 512*cq_b[o]
// ---------------------------------------------------------------------------
__global__ __launch_bounds__(256)
void qsum_kernel(const float* __restrict__ cqw, const float* __restrict__ cqb,
                 const float* __restrict__ asum, float* __restrict__ qsum)
{
    int o = blockIdx.x * 4 + (threadIdx.x >> 6);
    int lane = threadIdx.x & 63;
    float a0 = 0, a1 = 0, a2 = 0, a3 = 0;
    for (int j = 0; j < 16; j++) {
        int e = lane + j * 64;
        float wv = cqw[(long)o * 1024 + e];
        a0 += wv * asum[e];
        a1 += wv * asum[1024 + e];
        a2 += wv * asum[2048 + e];
        a3 += wv * asum[3072 + e];
    }
    for (int t = 32; t; t >>= 1) {
        a0 += __shfl_xor(a0, t); a1 += __shfl_xor(a1, t);
        a2 += __shfl_xor(a2, t); a3 += __shfl_xor(a3, t);
    }
    if (!lane) {
        float bb = 512.f * cqb[o];
        qsum[o] = a0 + bb; qsum[1024 + o] = a1 + bb;
        qsum[2048 + o] = a2 + bb; qsum[3072 + o] = a3 + bb;
    }
}

// ---------------------------------------------------------------------------
// cross stage A: s1[bh][m]
// ---------------------------------------------------------------------------
__global__ __launch_bounds__(256)
void s1_kernel(const bf16* __restrict__ kc, const float* __restrict__ qsum,
               float* __restrict__ s1)
{
    int bh = blockIdx.x, b = bh >> 4, h = bh & 15;
    int m = blockIdx.y * 256 + threadIdx.x;
    __shared__ float qd[64];
    if (threadIdx.x < 64) qd[threadIdx.x] = qsum[b * 1024 + threadIdx.x * 16 + h];
    __syncthreads();
    const bf16* kcb = kc + (long)b * 2048 * 1024 + (long)h * 2048 + m;
    float acc = 0.f;
#pragma unroll 8
    for (int d = 0; d < 64; d++) acc += qd[d] * b2f(kcb[(long)d * 16 * 2048]);
    s1[(long)bh * 2048 + m] = acc * 0.125f;
}

// ---------------------------------------------------------------------------
// cross stage B: per (b,h,n) row max & expsum
// ---------------------------------------------------------------------------
__global__ __launch_bounds__(256)
void bsum_kernel(const bf16* __restrict__ kc, const float* __restrict__ s1,
                 float* __restrict__ rmax, float* __restrict__ rsum)
{
    int bh = blockIdx.x >> 6, n = blockIdx.x & 63;
    int b = bh >> 4, h = bh & 15;
    int tid = threadIdx.x, lane = tid & 63, w = tid >> 6;
    const bf16* row = kc + (long)b * 2048 * 1024 + (long)(n * 16 + h) * 2048;
    const float* s1r = s1 + (long)bh * 2048;
    float t[8];
    float mx = -1e30f;
#pragma unroll
    for (int i = 0; i < 8; i++) {
        int m = tid + i * 256;
        t[i] = b2f(row[m]) * s1r[m];
        mx = fmaxf(mx, t[i]);
    }
    __shared__ float redm[4], reds[4];
    for (int o = 32; o; o >>= 1) mx = fmaxf(mx, __shfl_xor(mx, o));
    if (!lane) redm[w] = mx;
    __syncthreads();
    mx = fmaxf(fmaxf(redm[0], redm[1]), fmaxf(redm[2], redm[3]));
    float s = 0.f;
#pragma unroll
    for (int i = 0; i < 8; i++) s += __expf(t[i] - mx);
    for (int o = 32; o; o >>= 1) s += __shfl_xor(s, o);
    if (!lane) reds[w] = s;
    __syncthreads();
    if (!tid) {
        rmax[bh * 64 + n] = mx;
        rsum[bh * 64 + n] = reds[0] + reds[1] + reds[2] + reds[3];
    }
}

// ---------------------------------------------------------------------------
// cross stage C: wpr[bh][m]
// ---------------------------------------------------------------------------
__global__ __launch_bounds__(256)
void wpr_kernel(const bf16* __restrict__ kc, const float* __restrict__ s1,
                const float* __restrict__ rmax, const float* __restrict__ rsum,
                const float* __restrict__ dw, float* __restrict__ wpr)
{
    int bh = blockIdx.x, b = bh >> 4, h = bh & 15;
    int m = blockIdx.y * 256 + threadIdx.x;
    __shared__ float cf[64], cm[64];
    if (threadIdx.x < 64) {
        cf[threadIdx.x] = dw[threadIdx.x] / rsum[bh * 64 + threadIdx.x];
        cm[threadIdx.x] = rmax[bh * 64 + threadIdx.x];
    }
    __syncthreads();
    float s1v = s1[(long)bh * 2048 + m];
    const bf16* kcb = kc + (long)b * 2048 * 1024 + (long)h * 2048 + m;
    float acc = 0.f;
#pragma unroll 8
    for (int n = 0; n < 64; n++)
        acc += cf[n] * __expf(b2f(kcb[(long)n * 16 * 2048]) * s1v - cm[n]);
    wpr[(long)bh * 2048 + m] = acc;
}

// ---------------------------------------------------------------------------
// cross stage D: outs[b, d*16+h] = sum_m wpr[bh][m]*vc[b, d*16+h, m] + db
// ---------------------------------------------------------------------------
__global__ __launch_bounds__(256)
void cout_kernel(const bf16* __restrict__ vc, const float* __restrict__ wpr,
                 const float* __restrict__ db, float* __restrict__ outs)
{
    int bh = blockIdx.x >> 2, dg = blockIdx.x & 3;
    int b = bh >> 4, h = bh & 15;
    int tid = threadIdx.x, lane = tid & 63, w = tid >> 6;
    __shared__ float lwpr[2048];
#pragma unroll
    for (int i = 0; i < 8; i++) lwpr[tid + i * 256] = wpr[(long)bh * 2048 + tid + i * 256];
    __syncthreads();
#pragma unroll
    for (int dd = 0; dd < 4; dd++) {
        int d = dg * 16 + w * 4 + dd;
        int o = d * 16 + h;
        const bf16* vrow = vc + (long)b * 2048 * 1024 + (long)o * 2048;
        float acc = 0.f;
#pragma unroll
        for (int j = 0; j < 4; j++) {
            int m = j * 512 + lane * 8;
            short8 vv = *(const short8*)&vrow[m];
#pragma unroll
            for (int k = 0; k < 8; k++) {
                bf16 bb = __builtin_bit_cast(bf16, (unsigned short)vv[k]);
                acc += lwpr[m + k] * b2f(bb);
            }
        }
        for (int t2 = 32; t2; t2 >>= 1) acc += __shfl_xor(acc, t2);
        if (!lane) outs[b * 1024 + o] = acc + db[0];
    }
}

// ---------------------------------------------------------------------------
extern "C" void kernel_launch(void* const* d_in, const int* in_sizes, int n_in,
                              void* d_out, int out_size, void* d_ws, size_t ws_size,
                              hipStream_t stream)
{
    const float* tgt  = (const float*)d_in[0];
    const float* mem  = (const float*)d_in[1];
    const float* pos  = (const float*)d_in[2];
    const float* qp   = (const float*)d_in[3];
    const float* ipw  = (const float*)d_in[4];
    const float* ipb  = (const float*)d_in[5];
    const float* outw = (const float*)d_in[6];
    const float* outb = (const float*)d_in[7];
    const float* cqw  = (const float*)d_in[8];
    const float* cqb  = (const float*)d_in[9];
    const float* ckw  = (const float*)d_in[10];
    const float* ckb  = (const float*)d_in[11];
    const float* cvw  = (const float*)d_in[12];
    const float* cvb  = (const float*)d_in[13];
    const float* dww  = (const float*)d_in[14];
    const float* dwb  = (const float*)d_in[15];
    const float* l1w  = (const float*)d_in[16];
    const float* l1b  = (const float*)d_in[17];
    const float* l2w  = (const float*)d_in[18];
    const float* l2b  = (const float*)d_in[19];
    const float* n1g  = (const float*)d_in[20];
    const float* n1b  = (const float*)d_in[21];
    const float* n2g  = (const float*)d_in[22];
    const float* n2b  = (const float*)d_in[23];
    const float* n3g  = (const float*)d_in[24];
    const float* n3b  = (const float*)d_in[25];

    char* ws = (char*)d_ws;
    auto MB = [](long x) { return x << 20; };
    bf16* w_ip    = (bf16*)(ws + MB(0));    // 6 MB
    bf16* w_out   = (bf16*)(ws + MB(6));    // 2 MB
    bf16* w_ck    = (bf16*)(ws + MB(8));    // 2 MB
    bf16* w_cv    = (bf16*)(ws + MB(10));   // 2 MB
    bf16* w_l1    = (bf16*)(ws + MB(12));   // 4 MB
    bf16* w_l2    = (bf16*)(ws + MB(16));   // 4 MB
    bf16* qkin    = (bf16*)(ws + MB(20));   // 4 MB
    bf16* tgtb    = (bf16*)(ws + MB(24));   // 4 MB
    bf16* memposb = (bf16*)(ws + MB(28));   // 16 MB
    bf16* memb    = (bf16*)(ws + MB(44));   // 16 MB
    bf16* qkbuf   = (bf16*)(ws + MB(60));   // 8 MB
    bf16* vtb     = (bf16*)(ws + MB(68));   // 4 MB
    bf16* kcb     = (bf16*)(ws + MB(72));   // 16 MB
    bf16* ctxb    = (bf16*)(ws + MB(104));  // 4 MB
    bf16* atmpb   = (bf16*)(ws + MB(108));  // 4 MB (LN1 input, bf16)
    float* s1buf  = (float*)(ws + MB(108)); // 512 KB (reuses slot after LN1)
    float* wprbuf = (float*)(ws + MB(109)); // 512 KB
    float* rmax   = (float*)(ws + MB(110));              // 16 KB
    float* rsum   = (float*)(ws + MB(110) + (64 << 10)); // 16 KB
    float* part   = (float*)(ws + MB(111)); // 256 KB
    float* tgt1   = (float*)(ws + MB(116)); // 8 MB
    float* asum   = (float*)(ws + MB(124)); // 16 KB
    float* qsum   = (float*)(ws + MB(125)); // 16 KB
    bf16* vcb     = (bf16*)(ws + MB(126));  // 16 MB
    float* outs   = (float*)(ws + MB(142)); // 16 KB
    float* tgt2   = (float*)(ws + MB(143)); // 8 MB
    bf16* tgt2b   = (bf16*)(ws + MB(151));  // 4 MB
    bf16* ff1b    = (bf16*)(ws + MB(155));  // 8 MB
    bf16* ff2b    = (bf16*)(ws + MB(163));  // 4 MB

    const int BIGZ = 1000000, BIGN = 1 << 30;

    // --- prepass: dedup f32->bf16 conversions (R14 full segment set) ---
    Cvt2Args ca{};
    ca.s[0] = {ipw,  nullptr, w_ip,    nullptr, 1536};
    ca.s[1] = {outw, nullptr, w_out,   nullptr, 512};
    ca.s[2] = {ckw,  nullptr, w_ck,    nullptr, 512};
    ca.s[3] = {cvw,  nullptr, w_cv,    nullptr, 512};
    ca.s[4] = {l1w,  nullptr, w_l1,    nullptr, 1024};
    ca.s[5] = {l2w,  nullptr, w_l2,    nullptr, 1024};
    ca.s[6] = {tgt,  qp,      qkin,    tgtb,    1024};
    ca.s[7] = {mem,  pos,     memposb, memb,    4096};
    cvt_kernel<<<dim3(2048, 1, 1), 256, 0, stream>>>(ca);

    // --- fused qkv projection: [2048,1024]x[1024,3072] (768 blocks) ---
    gemm_nt<64, 128><<<dim3(768, 1, 1), 256, 0, stream>>>(
        qkin, w_ip, nullptr, qkbuf, ipb,
        tgtb, nullptr, vtb, nullptr,
        32, 24,
        1024, 1024, 1024, 2048,
        0, 0, 0, 0, 0, 0, 1, BIGZ, 2048, 1.f, 1, 3);

    // --- fused flash self-attention ---
    flash_attn<<<dim3(256, 1, 1), 512, 0, stream>>>(qkbuf, vtb, ctxb);

    // --- out projection -> atmpb bf16 ---
    gemm_nt<64, 128><<<dim3(256, 1, 1), 256, 0, stream>>>(
        ctxb, w_out, nullptr, atmpb, outb,
        nullptr, nullptr, nullptr, nullptr,
        32, 8,
        1024, 1024, 1024, 1024,
        0, 0, 0, 0, 0, 0, 1, BIGZ, BIGN, 1.f, 1, 1);

    // --- LN1: tgt1 = LN(bf16(atmp) + tgt) ---
    ln_kernel<<<dim3(2048, 1, 1), 256, 0, stream>>>(
        nullptr, atmpb, tgt, nullptr, n1g, n1b, tgt1, nullptr);

    // --- qc path ---
    asum_part_kernel<<<dim3(256, 1, 1), 256, 0, stream>>>(tgt1, qp, part);
    asum_reduce_kernel<<<dim3(16, 1, 1), 256, 0, stream>>>(part, asum);
    qsum_kernel<<<dim3(256, 1, 1), 256, 0, stream>>>(cqw, cqb, asum, qsum);

    // --- fused kc+vc: 256x256 tile, BK=64 (256 blocks x 512 thr) ---
    kcvc_gemm<<<dim3(256, 1, 1), 512, 0, stream>>>(
        w_ck, w_cv, memposb, memb, kcb, vcb, ckb, cvb);

    // --- cross attention stages ---
    s1_kernel<<<dim3(64, 8, 1), 256, 0, stream>>>(kcb, qsum, s1buf);
    bsum_kernel<<<dim3(4096, 1, 1), 256, 0, stream>>>(kcb, s1buf, rmax, rsum);
    wpr_kernel<<<dim3(64, 8, 1), 256, 0, stream>>>(kcb, s1buf, rmax, rsum, dww, wprbuf);
    cout_kernel<<<dim3(256, 1, 1), 256, 0, stream>>>(vcb, wprbuf, dwb, outs);

    // --- LN2 ---
    ln_kernel<<<dim3(2048, 1, 1), 256, 0, stream>>>(
        tgt1, nullptr, nullptr, outs, n2g, n2b, tgt2, tgt2b);

    // --- FFN ---
    gemm_nt<64, 128><<<dim3(512, 1, 1), 256, 0, stream>>>(
        tgt2b, w_l1, nullptr, ff1b, l1b,
        nullptr, nullptr, nullptr, nullptr,
        32, 16,
        1024, 1024, 1024, 2048,
        0, 0, 0, 0, 0, 0, 1, BIGZ, BIGN, 1.f, 2, 2);

    gemm_nt<64, 128><<<dim3(256, 1, 1), 256, 0, stream>>>(
        ff1b, w_l2, nullptr, ff2b, l2b,
        nullptr, nullptr, nullptr, nullptr,
        32, 8,
        2048, 2048, 2048, 1024,
        0, 0, 0, 0, 0, 0, 1, BIGZ, BIGN, 1.f, 1, 1);

    // --- LN3 -> d_out ---
    ln_kernel<<<dim3(2048, 1, 1), 256, 0, stream>>>(
        nullptr, ff2b, tgt2, nullptr, n3g, n3b, (float*)d_out, nullptr);
}

// Round 19
// 249.338 us; speedup vs baseline: 1.2489x; 1.0381x over previous
//
#include <hip/hip_runtime.h>
#include <hip/hip_bf16.h>

typedef __hip_bfloat16 bf16;
typedef short short8 __attribute__((ext_vector_type(8)));
typedef float f32x4 __attribute__((ext_vector_type(4)));

#define Lq 512
#define Sm 2048
#define Bb 4
#define Ee 1024
#define Hh 16
#define FFd 2048
#define HDd 64

static __device__ __forceinline__ float b2f(bf16 x) { return __bfloat162float(x); }
static __device__ __forceinline__ bf16 f2b(float x) { return __float2bfloat16(x); }
static __device__ __forceinline__ unsigned short bits(bf16 x) {
    return __builtin_bit_cast(unsigned short, x);
}
static __device__ __forceinline__ float us2f(unsigned short u) {
    return b2f(__builtin_bit_cast(bf16, u));
}

static __device__ __forceinline__ void gload16(const void* g, void* l) {
    __builtin_amdgcn_global_load_lds(
        (const __attribute__((address_space(1))) unsigned int*)g,
        (__attribute__((address_space(3))) unsigned int*)l, 16, 0, 0);
}

static __device__ __forceinline__ short8 pack8(float4 a0, float4 a1) {
    short8 u;
    u[0] = (short)bits(f2b(a0.x)); u[1] = (short)bits(f2b(a0.y));
    u[2] = (short)bits(f2b(a0.z)); u[3] = (short)bits(f2b(a0.w));
    u[4] = (short)bits(f2b(a1.x)); u[5] = (short)bits(f2b(a1.y));
    u[6] = (short)bits(f2b(a1.z)); u[7] = (short)bits(f2b(a1.w));
    return u;
}

struct Cvt2Seg { const float* a; const float* b; bf16* d; bf16* d2; int nblk; };
struct Cvt2Args { Cvt2Seg s[8]; };

// ---------------------------------------------------------------------------
// kc+vc GEMM, 256x256 tile, BK=64, 2 LDS buffers (R14 configuration).
// ---------------------------------------------------------------------------
__global__ __launch_bounds__(512, 2)
void kcvc_gemm(const bf16* __restrict__ wk, const bf16* __restrict__ wv,
               const bf16* __restrict__ mp, const bf16* __restrict__ mo,
               bf16* __restrict__ kc, bf16* __restrict__ vc,
               const float* __restrict__ kb, const float* __restrict__ vb)
{
    constexpr int BK = 64;
    __shared__ bf16 lA[2][256 * BK];
    __shared__ bf16 lB[2][256 * BK];

    const int tid  = threadIdx.x;
    const int lane = tid & 63;
    const int wm = (tid >> 6) >> 2;
    const int wn = (tid >> 6) & 3;

    int bid = (blockIdx.x & 7) * 32 + (blockIdx.x >> 3);
    const int bx = bid & 3;
    const int by = (bid >> 2) & 7;
    const int z  = bid >> 5;

    const bool isv = z >= 4;
    const int  b   = isv ? z - 4 : z;
    const bf16*  A    = isv ? wv : wk;
    const bf16*  B    = (isv ? mo : mp) + b * 1024;
    bf16*        C    = (isv ? vc : kc) + (long)b * 2097152;
    const float* bias = isv ? vb : kb;

    const int m0 = bx * 256, n0 = by * 256;
    const bf16* Abase = A + (long)m0 * 1024;
    const bf16* Bbase = B + (long)n0 * 4096;

    const int kgrp = lane >> 4, l16 = lane & 15;
    const int rsw = l16 & 7;

    auto stage = [&](int buf, int k0) {
#pragma unroll
        for (int r = 0; r < 4; r++) {
            int c = r * 512 + tid;
            int row = c >> 3;
            int ss = (c & 7) ^ (row & 7);
            gload16(Abase + (long)row * 1024 + k0 + ss * 8, &lA[buf][c * 8]);
        }
#pragma unroll
        for (int r = 0; r < 4; r++) {
            int c = r * 512 + tid;
            int row = c >> 3;
            int ss = (c & 7) ^ (row & 7);
            gload16(Bbase + (long)row * 4096 + k0 + ss * 8, &lB[buf][c * 8]);
        }
    };

    f32x4 acc[8][4];
#pragma unroll
    for (int i = 0; i < 8; i++)
#pragma unroll
        for (int j = 0; j < 4; j++) acc[i][j] = f32x4{0.f, 0.f, 0.f, 0.f};

    stage(0, 0);
    asm volatile("s_waitcnt vmcnt(0)" ::: "memory");
    __builtin_amdgcn_s_barrier();

    constexpr int NT = 16;
    for (int t = 0; t < NT; t++) {
        if (t + 1 < NT) stage((t + 1) & 1, (t + 1) * BK);

        const bf16* la = lA[t & 1];
        const bf16* lb = lB[t & 1];
#pragma unroll
        for (int h = 0; h < 2; h++) {
            const int sd = ((h * 4 + kgrp) ^ rsw) * 8;
            short8 af[8], bv[4];
#pragma unroll
            for (int i = 0; i < 8; i++)
                af[i] = *(const short8*)&la[(wm * 128 + i * 16 + l16) * BK + sd];
#pragma unroll
            for (int j = 0; j < 4; j++)
                bv[j] = *(const short8*)&lb[(wn * 64 + j * 16 + l16) * BK + sd];
            __builtin_amdgcn_s_setprio(1);
#pragma unroll
            for (int i = 0; i < 8; i++)
#pragma unroll
                for (int j = 0; j < 4; j++)
                    acc[i][j] = __builtin_amdgcn_mfma_f32_16x16x32_bf16(af[i], bv[j], acc[i][j], 0, 0, 0);
            __builtin_amdgcn_s_setprio(0);
        }

        asm volatile("s_waitcnt vmcnt(0)" ::: "memory");
        __builtin_amdgcn_s_barrier();
    }

#pragma unroll
    for (int i = 0; i < 8; i++) {
#pragma unroll
        for (int j = 0; j < 4; j++) {
#pragma unroll
            for (int r = 0; r < 4; r++) {
                int row = m0 + wm * 128 + i * 16 + kgrp * 4 + r;
                int col = n0 + wn * 64 + j * 16 + l16;
                float v = acc[i][j][r] + bias[row];
                float v2 = __shfl_xor(v, 1);
                if (!(l16 & 1)) {
                    unsigned int pk = (unsigned int)bits(f2b(v)) |
                                      ((unsigned int)bits(f2b(v2)) << 16);
                    *(unsigned int*)&C[(long)row * 2048 + col] = pk;
                }
            }
        }
    }
}

// ---------------------------------------------------------------------------
// HYBRID: flash self-attention (blocks 0..255, unchanged body) + deferred
// f32->bf16 conversions (blocks 256..767, grid-stride; 4096 floats/chunk).
// The cvt segments' consumers (outproj/kcvc/FFN) all launch after this
// kernel, so stream order preserves dependencies. Fills the wave slots and
// memory pipe that flash (1 block/CU) leaves idle.
// ---------------------------------------------------------------------------
__global__ __launch_bounds__(512, 2)
void flash_cvt(const bf16* __restrict__ qk, const bf16* __restrict__ vt,
               bf16* __restrict__ ctx, Cvt2Args args)
{
    __shared__ bf16 lQ[128 * 64];
    __shared__ bf16 lK[2][64 * 64];
    __shared__ bf16 lV[2][64 * 64];
    __shared__ bf16 lP[128 * 64];
    __shared__ float scb[128];

    if (blockIdx.x >= 256) {
        const int cb = blockIdx.x - 256;       // 0..511
        for (int ci = cb; ci < 3840; ci += 512) {
            int rem = ci;
            int si = 0;
            while (si < 5 && rem >= args.s[si].nblk) { rem -= args.s[si].nblk; si++; }
            Cvt2Seg sg = args.s[si];
            const long i = (long)rem * 4096 + threadIdx.x * 8;

            float4 a0 = *(const float4*)(sg.a + i);
            float4 a1 = *(const float4*)(sg.a + i + 4);
            float4 s0 = a0, s1 = a1;
            if (sg.b) {
                float4 b0 = *(const float4*)(sg.b + i);
                float4 b1 = *(const float4*)(sg.b + i + 4);
                s0.x += b0.x; s0.y += b0.y; s0.z += b0.z; s0.w += b0.w;
                s1.x += b1.x; s1.y += b1.y; s1.z += b1.z; s1.w += b1.w;
            }
            *(short8*)((unsigned short*)sg.d + i) = pack8(s0, s1);
            if (sg.d2) {
                *(short8*)((unsigned short*)sg.d2 + i) = pack8(a0, a1);
            }
        }
        return;
    }

    const int tid  = threadIdx.x;
    const int lane = tid & 63;
    const int wq   = tid >> 6;
    const int kgrp = lane >> 4, l16 = lane & 15;

    const int qt = blockIdx.x & 3;
    const int bh = blockIdx.x >> 2;
    const int b = bh >> 4, h = bh & 15;
    const int L0 = qt * 128;

#pragma unroll
    for (int it = 0; it < 2; it++) {
        int c = it * 512 + tid;
        int rr = c >> 3, sl = c & 7, ss = sl ^ (rr & 7);
        gload16(qk + ((long)(L0 + rr) * 4 + b) * 2048 + h * 64 + ss * 8,
                &lQ[(it * 512 + wq * 64) * 8]);
    }

    auto stageKV = [&](int buf, int st) {
        int rr = tid >> 3, sl = tid & 7, ss = sl ^ (rr & 7);
        gload16(qk + ((long)(st * 64 + rr) * 4 + b) * 2048 + 1024 + h * 64 + ss * 8,
                &lK[buf][(wq * 64) * 8]);
        gload16(vt + ((long)(b * 1024 + h * 64 + rr)) * 512 + st * 64 + ss * 8,
                &lV[buf][(wq * 64) * 8]);
    };

    auto frag = [&](const bf16* base, int row, int kk) {
        return *(const short8*)&base[row * 64 + (((kk * 4 + kgrp) ^ (l16 & 7)) * 8)];
    };

    f32x4 acc_o[4];
#pragma unroll
    for (int j = 0; j < 4; j++) acc_o[j] = f32x4{0.f, 0.f, 0.f, 0.f};
    float m_run = -1e30f, l_run = 0.f;

    stageKV(0, 0);
    asm volatile("s_waitcnt vmcnt(0)" ::: "memory");
    __builtin_amdgcn_s_barrier();

    int buf = 0;
    for (int st = 0; st < 8; st++) {
        if (st < 7) stageKV(buf ^ 1, st + 1);

        f32x4 accs[4];
#pragma unroll
        for (int fm = 0; fm < 4; fm++) accs[fm] = f32x4{0.f, 0.f, 0.f, 0.f};
        __builtin_amdgcn_s_setprio(1);
#pragma unroll
        for (int kk = 0; kk < 2; kk++) {
            short8 bq = frag(lQ, wq * 16 + l16, kk);
#pragma unroll
            for (int fm = 0; fm < 4; fm++) {
                short8 af = frag(lK[buf], fm * 16 + l16, kk);
                accs[fm] = __builtin_amdgcn_mfma_f32_16x16x32_bf16(af, bq, accs[fm], 0, 0, 0);
            }
        }
        __builtin_amdgcn_s_setprio(0);

        float v[4][4], p[4][4];
        float tmax = -1e30f;
#pragma unroll
        for (int fm = 0; fm < 4; fm++)
#pragma unroll
            for (int r = 0; r < 4; r++) {
                v[fm][r] = accs[fm][r] * 0.125f;
                tmax = fmaxf(tmax, v[fm][r]);
            }
        tmax = fmaxf(tmax, __shfl_xor(tmax, 16));
        tmax = fmaxf(tmax, __shfl_xor(tmax, 32));
        float m_new = fmaxf(m_run, tmax);
        float sc = __expf(m_run - m_new);
        float sum = 0.f;
#pragma unroll
        for (int fm = 0; fm < 4; fm++)
#pragma unroll
            for (int r = 0; r < 4; r++) {
                p[fm][r] = __expf(v[fm][r] - m_new);
                sum += p[fm][r];
            }
        sum += __shfl_xor(sum, 16);
        sum += __shfl_xor(sum, 32);
        l_run = l_run * sc + sum;
        m_run = m_new;

        if (!kgrp) scb[wq * 16 + l16] = sc;
        asm volatile("s_waitcnt lgkmcnt(0)" ::: "memory");
        __builtin_amdgcn_sched_barrier(0);
        float sc2[4];
#pragma unroll
        for (int r = 0; r < 4; r++) sc2[r] = scb[wq * 16 + kgrp * 4 + r];
#pragma unroll
        for (int fn = 0; fn < 4; fn++)
#pragma unroll
            for (int r = 0; r < 4; r++) acc_o[fn][r] *= sc2[r];

#pragma unroll
        for (int fm = 0; fm < 4; fm++) {
            int l = wq * 16 + l16;
            int sp = (fm * 2 + (kgrp >> 1)) ^ (l16 & 7);
            uint2 pk;
            pk.x = (unsigned int)bits(f2b(p[fm][0])) | ((unsigned int)bits(f2b(p[fm][1])) << 16);
            pk.y = (unsigned int)bits(f2b(p[fm][2])) | ((unsigned int)bits(f2b(p[fm][3])) << 16);
            *(uint2*)&lP[l * 64 + sp * 8 + (kgrp & 1) * 4] = pk;
        }
        asm volatile("s_waitcnt lgkmcnt(0)" ::: "memory");
        __builtin_amdgcn_sched_barrier(0);

        __builtin_amdgcn_s_setprio(1);
#pragma unroll
        for (int kk = 0; kk < 2; kk++) {
            short8 ap = frag(lP, wq * 16 + l16, kk);
#pragma unroll
            for (int fn = 0; fn < 4; fn++) {
                short8 bvf = frag(lV[buf], fn * 16 + l16, kk);
                acc_o[fn] = __builtin_amdgcn_mfma_f32_16x16x32_bf16(ap, bvf, acc_o[fn], 0, 0, 0);
            }
        }
        __builtin_amdgcn_s_setprio(0);

        asm volatile("s_waitcnt vmcnt(0)" ::: "memory");
        __builtin_amdgcn_s_barrier();
        buf ^= 1;
    }

    if (!kgrp) scb[wq * 16 + l16] = 1.f / l_run;
    asm volatile("s_waitcnt lgkmcnt(0)" ::: "memory");
    __builtin_amdgcn_sched_barrier(0);
    float inv[4];
#pragma unroll
    for (int r = 0; r < 4; r++) inv[r] = scb[wq * 16 + kgrp * 4 + r];
#pragma unroll
    for (int fn = 0; fn < 4; fn++) {
#pragma unroll
        for (int r = 0; r < 4; r++) {
            int lg = L0 + wq * 16 + kgrp * 4 + r;
            int d  = fn * 16 + l16;
            float vv = acc_o[fn][r] * inv[r];
            float v2 = __shfl_xor(vv, 1);
            if (!(l16 & 1)) {
                unsigned int pk = (unsigned int)bits(f2b(vv)) |
                                  ((unsigned int)bits(f2b(v2)) << 16);
                *(unsigned int*)&ctx[((long)lg * 4 + b) * 1024 + h * 64 + d] = pk;
            }
        }
    }
}

// ---------------------------------------------------------------------------
// NT bf16 MFMA GEMM — BK=64 / 2-buffer / h-split (unchanged).
// ---------------------------------------------------------------------------
template<int BM, int BN>
__global__ __launch_bounds__(256)
void gemm_nt(const bf16* __restrict__ A, const bf16* __restrict__ Bw,
             float* __restrict__ Cf, bf16* __restrict__ Cb,
             const float* __restrict__ bias,
             const bf16* __restrict__ A2, const bf16* __restrict__ B2,
             bf16* __restrict__ Cb2, const float* __restrict__ bias2,
             int gx, int gy,
             int K, long lda, long ldb, long ldc,
             long sA1, long sA2, long sB1, long sB2, long sC1, long sC2,
             int zdiv, int zsplit, int nsplit, float alpha, int mode, int mode2)
{
    constexpr int BK = 64;
    constexpr int RA = BM / 32, RB = BN / 32;
    __shared__ bf16 lA[2][BM * BK];
    __shared__ bf16 lB[2][BN * BK];

    const int tid  = threadIdx.x;
    const int lane = tid & 63;
    const int wave = tid >> 6;
    const int wm = wave >> 1, wn = wave & 1;
    constexpr int RM = BM / 2, RN = BN / 2;
    constexpr int FM = RM / 16, FN = RN / 16;

    const int nwg = gridDim.x;
    const int cpx = nwg >> 3;
    int bid = (blockIdx.x & 7) * cpx + (blockIdx.x >> 3);
    const int bx = bid % gx;
    int tmp = bid / gx;
    const int by = tmp % gy;
    const int z  = tmp / gy;

    const int m0 = bx * BM;
    const int n0 = by * BN;

    const bool use2 = (z >= zsplit) || (n0 >= nsplit);
    const int  zz   = (z >= zsplit) ? z - zsplit : z;
    const bf16*  Ap = (use2 && A2)    ? A2    : A;
    const bf16*  Bp = (use2 && B2)    ? B2    : Bw;
    const float* bp = (use2 && bias2) ? bias2 : bias;
    const int    md = use2 ? mode2 : mode;
    bf16*        Co = (use2 && Cb2)   ? Cb2   : Cb;

    const long offA = (long)(zz / zdiv) * sA1 + (long)(zz % zdiv) * sA2;
    const long offB = (long)(zz / zdiv) * sB1 + (long)(zz % zdiv) * sB2;
    const long offC = (long)(zz / zdiv) * sC1 + (long)(zz % zdiv) * sC2;

    const bf16* Abase = Ap + offA + (long)m0 * lda;
    const bf16* Bbase = Bp + offB + (long)n0 * ldb;

    const int kgrp = lane >> 4;
    const int l16  = lane & 15;
    const int rsw  = l16 & 7;

    auto stage = [&](int buf, int k0) {
#pragma unroll
        for (int r = 0; r < RA; r++) {
            int c = r * 256 + tid;
            int row = c >> 3;
            int ss = (c & 7) ^ (row & 7);
            gload16(Abase + (long)row * lda + k0 + ss * 8, &lA[buf][c * 8]);
        }
#pragma unroll
        for (int r = 0; r < RB; r++) {
            int c = r * 256 + tid;
            int row = c >> 3;
            int ss = (c & 7) ^ (row & 7);
            gload16(Bbase + (long)row * ldb + k0 + ss * 8, &lB[buf][c * 8]);
        }
    };

    f32x4 acc[FM][FN];
#pragma unroll
    for (int i = 0; i < FM; i++)
#pragma unroll
        for (int j = 0; j < FN; j++) acc[i][j] = f32x4{0.f, 0.f, 0.f, 0.f};

    const int nt = K / BK;
    stage(0, 0);
    asm volatile("s_waitcnt vmcnt(0)" ::: "memory");
    __builtin_amdgcn_s_barrier();

    for (int t = 0; t < nt; t++) {
        if (t + 1 < nt) stage((t + 1) & 1, (t + 1) * BK);

        const bf16* la = lA[t & 1];
        const bf16* lb = lB[t & 1];
#pragma unroll
        for (int h = 0; h < 2; h++) {
            const int sd = ((h * 4 + kgrp) ^ rsw) * 8;
            short8 af[FM], bv[FN];
#pragma unroll
            for (int i = 0; i < FM; i++)
                af[i] = *(const short8*)&la[(wm * RM + i * 16 + l16) * BK + sd];
#pragma unroll
            for (int j = 0; j < FN; j++)
                bv[j] = *(const short8*)&lb[(wn * RN + j * 16 + l16) * BK + sd];
            __builtin_amdgcn_s_setprio(1);
#pragma unroll
            for (int i = 0; i < FM; i++)
#pragma unroll
                for (int j = 0; j < FN; j++)
                    acc[i][j] = __builtin_amdgcn_mfma_f32_16x16x32_bf16(af[i], bv[j], acc[i][j], 0, 0, 0);
            __builtin_amdgcn_s_setprio(0);
        }

        asm volatile("s_waitcnt vmcnt(0)" ::: "memory");
        __builtin_amdgcn_s_barrier();
    }

#pragma unroll
    for (int i = 0; i < FM; i++) {
#pragma unroll
        for (int j = 0; j < FN; j++) {
#pragma unroll
            for (int r = 0; r < 4; r++) {
                int row = m0 + wm * RM + i * 16 + kgrp * 4 + r;
                int col = n0 + wn * RN + j * 16 + l16;
                float v = alpha * acc[i][j][r] + (bp ? bp[col] : 0.f);
                float v2 = __shfl_xor(v, 1);
                if (md == 0) {
                    if (!(l16 & 1)) {
                        float2 pv = {v, v2};
                        *(float2*)&Cf[offC + (long)row * ldc + col] = pv;
                    }
                } else if (md == 1) {
                    if (!(l16 & 1)) {
                        unsigned int pk = (unsigned int)bits(f2b(v)) |
                                          ((unsigned int)bits(f2b(v2)) << 16);
                        *(unsigned int*)&Co[offC + (long)row * ldc + col] = pk;
                    }
                } else if (md == 2) {
                    if (!(l16 & 1)) {
                        unsigned int pk = (unsigned int)bits(f2b(fmaxf(v, 0.f))) |
                                          ((unsigned int)bits(f2b(fmaxf(v2, 0.f))) << 16);
                        *(unsigned int*)&Co[offC + (long)row * ldc + col] = pk;
                    }
                } else {
                    int o = col - nsplit;
                    Cb2[((long)(row & 3) * 1024 + o) * 512 + (row >> 2)] = f2b(v);
                }
            }
        }
    }
}

// ---------------------------------------------------------------------------
// f32->bf16 convert prepass — EARLY segments only (ipw + tgt/qp, the inputs
// qkv needs immediately). Deferred segments run inside flash_cvt.
// ---------------------------------------------------------------------------
__global__ __launch_bounds__(256)
void cvt_kernel(Cvt2Args args)
{
    for (int ci = blockIdx.x; ci < 2560; ci += 2048) {
        int rem = ci;
        int si = 0;
        while (si < 7 && rem >= args.s[si].nblk) { rem -= args.s[si].nblk; si++; }
        Cvt2Seg sg = args.s[si];
        const long i = (long)rem * 2048 + threadIdx.x * 8;

        float4 a0 = *(const float4*)(sg.a + i);
        float4 a1 = *(const float4*)(sg.a + i + 4);
        float4 s0 = a0, s1 = a1;
        if (sg.b) {
            float4 b0 = *(const float4*)(sg.b + i);
            float4 b1 = *(const float4*)(sg.b + i + 4);
            s0.x += b0.x; s0.y += b0.y; s0.z += b0.z; s0.w += b0.w;
            s1.x += b1.x; s1.y += b1.y; s1.z += b1.z; s1.w += b1.w;
        }
        *(short8*)((unsigned short*)sg.d + i) = pack8(s0, s1);
        if (sg.d2) {
            *(short8*)((unsigned short*)sg.d2 + i) = pack8(a0, a1);
        }
    }
}

// ---------------------------------------------------------------------------
// LayerNorm over E=1024: input x (f32) OR xB (bf16); + res (f32) / resb.
// ---------------------------------------------------------------------------
__global__ __launch_bounds__(256)
void ln_kernel(const float* __restrict__ x, const bf16* __restrict__ xB,
               const float* __restrict__ res, const float* __restrict__ resb,
               const float* __restrict__ g, const float* __restrict__ be,
               float* __restrict__ outF, bf16* __restrict__ outB)
{
    long row = blockIdx.x;
    int tid = threadIdx.x, lane = tid & 63, w = tid >> 6;
    float vv[4];
    if (x) {
        float4 xv = *(const float4*)(x + row * 1024 + tid * 4);
        vv[0] = xv.x; vv[1] = xv.y; vv[2] = xv.z; vv[3] = xv.w;
    } else {
        ushort4 xv = *(const ushort4*)((const unsigned short*)xB + row * 1024 + tid * 4);
        vv[0] = us2f(xv.x); vv[1] = us2f(xv.y); vv[2] = us2f(xv.z); vv[3] = us2f(xv.w);
    }
    if (res) {
        float4 rv = *(const float4*)(res + row * 1024 + tid * 4);
        vv[0] += rv.x; vv[1] += rv.y; vv[2] += rv.z; vv[3] += rv.w;
    }
    if (resb) {
        float4 rv = *(const float4*)(resb + (row & 3) * 1024 + tid * 4);
        vv[0] += rv.x; vv[1] += rv.y; vv[2] += rv.z; vv[3] += rv.w;
    }
    float s = vv[0] + vv[1] + vv[2] + vv[3];
    float q = vv[0] * vv[0] + vv[1] * vv[1] + vv[2] * vv[2] + vv[3] * vv[3];
    __shared__ float rs[4], rq[4];
    for (int o = 32; o; o >>= 1) { s += __shfl_xor(s, o); q += __shfl_xor(q, o); }
    if (!lane) { rs[w] = s; rq[w] = q; }
    __syncthreads();
    s = rs[0] + rs[1] + rs[2] + rs[3];
    q = rq[0] + rq[1] + rq[2] + rq[3];
    float mean = s * (1.f / 1024.f);
    float var  = q * (1.f / 1024.f) - mean * mean;
    float rstd = rsqrtf(var + 1e-5f);
    float4 gv = *(const float4*)(g + tid * 4);
    float4 bv = *(const float4*)(be + tid * 4);
    float o0 = (vv[0] - mean) * rstd * gv.x + bv.x;
    float o1 = (vv[1] - mean) * rstd * gv.y + bv.y;
    float o2 = (vv[2] - mean) * rstd * gv.z + bv.z;
    float o3 = (vv[3] - mean) * rstd * gv.w + bv.w;
    if (outF) {
        float4 ov = {o0, o1, o2, o3};
        *(float4*)(outF + row * 1024 + tid * 4) = ov;
    }
    if (outB) {
        ushort4 u;
        u.x = bits(f2b(o0)); u.y = bits(f2b(o1));
        u.z = bits(f2b(o2)); u.w = bits(f2b(o3));
        *reinterpret_cast<ushort4*>((unsigned short*)outB + row * 1024 + tid * 4) = u;
    }
}

// ---------------------------------------------------------------------------
// asum partials over L, then reduce
// ---------------------------------------------------------------------------
__global__ __launch_bounds__(256)
void asum_part_kernel(const float* __restrict__ t1, const float* __restrict__ qp,
                      float* __restrict__ part)
{
    int blk = blockIdx.x;
    int lc = blk >> 4, b = (blk >> 2) & 3, ec = blk & 3;
    int e = ec * 256 + threadIdx.x;
    float acc = 0.f;
#pragma unroll 4
    for (int l = lc * 32; l < lc * 32 + 32; l++) {
        long idx = ((long)(l * 4 + b)) * 1024 + e;
        acc += t1[idx] + qp[idx];
    }
    part[(lc * 4 + b) * 1024 + e] = acc;
}

__global__ __launch_bounds__(256)
void asum_reduce_kernel(const float* __restrict__ part, float* __restrict__ asum)
{
    int b = blockIdx.x >> 2, ec = blockIdx.x & 3;
    int e = ec * 256 + threadIdx.x;
    float acc = 0.f;
#pragma unroll
    for (int lc = 0; lc < 16; lc++) acc += part[(lc * 4 + b) * 1024 + e];
    asum[b * 1024 + e] = acc;
}

// ---------------------------------------------------------------------------
// qsum[b,o] = sum_e cq_w[o,e]*asum[b,e] + 512*cq_b[o]
// ---------------------------------------------------------------------------
__global__ __launch_bounds__(256)
void qsum_kernel(const float* __restrict__ cqw, const float* __restrict__ cqb,
                 const float* __restrict__ asum, float* __restrict__ qsum)
{
    int o = blockIdx.x * 4 + (threadIdx.x >> 6);
    int lane = threadIdx.x & 63;
    float a0 = 0, a1 = 0, a2 = 0, a3 = 0;
    for (int j = 0; j < 16; j++) {
        int e = lane + j * 64;
        float wv = cqw[(long)o * 1024 + e];
        a0 += wv * asum[e];
        a1 += wv * asum[1024 + e];
        a2 += wv * asum[2048 + e];
        a3 += wv * asum[3072 + e];
    }
    for (int t = 32; t; t >>= 1) {
        a0 += __shfl_xor(a0, t); a1 += __shfl_xor(a1, t);
        a2 += __shfl_xor(a2, t); a3 += __shfl_xor(a3, t);
    }
    if (!lane) {
        float bb = 512.f * cqb[o];
        qsum[o] = a0 + bb; qsum[1024 + o] = a1 + bb;
        qsum[2048 + o] = a2 + bb; qsum[3072 + o] = a3 + bb;
    }
}

// ---------------------------------------------------------------------------
// cross stage A: s1[bh][m]
// ---------------------------------------------------------------------------
__global__ __launch_bounds__(256)
void s1_kernel(const bf16* __restrict__ kc, const float* __restrict__ qsum,
               float* __restrict__ s1)
{
    int bh = blockIdx.x, b = bh >> 4, h = bh & 15;
    int m = blockIdx.y * 256 + threadIdx.x;
    __shared__ float qd[64];
    if (threadIdx.x < 64) qd[threadIdx.x] = qsum[b * 1024 + threadIdx.x * 16 + h];
    __syncthreads();
    const bf16* kcb = kc + (long)b * 2048 * 1024 + (long)h * 2048 + m;
    float acc = 0.f;
#pragma unroll 8
    for (int d = 0; d < 64; d++) acc += qd[d] * b2f(kcb[(long)d * 16 * 2048]);
    s1[(long)bh * 2048 + m] = acc * 0.125f;
}

// ---------------------------------------------------------------------------
// cross stage B: per (b,h,n) row max & expsum
// ---------------------------------------------------------------------------
__global__ __launch_bounds__(256)
void bsum_kernel(const bf16* __restrict__ kc, const float* __restrict__ s1,
                 float* __restrict__ rmax, float* __restrict__ rsum)
{
    int bh = blockIdx.x >> 6, n = blockIdx.x & 63;
    int b = bh >> 4, h = bh & 15;
    int tid = threadIdx.x, lane = tid & 63, w = tid >> 6;
    const bf16* row = kc + (long)b * 2048 * 1024 + (long)(n * 16 + h) * 2048;
    const float* s1r = s1 + (long)bh * 2048;
    float t[8];
    float mx = -1e30f;
#pragma unroll
    for (int i = 0; i < 8; i++) {
        int m = tid + i * 256;
        t[i] = b2f(row[m]) * s1r[m];
        mx = fmaxf(mx, t[i]);
    }
    __shared__ float redm[4], reds[4];
    for (int o = 32; o; o >>= 1) mx = fmaxf(mx, __shfl_xor(mx, o));
    if (!lane) redm[w] = mx;
    __syncthreads();
    mx = fmaxf(fmaxf(redm[0], redm[1]), fmaxf(redm[2], redm[3]));
    float s = 0.f;
#pragma unroll
    for (int i = 0; i < 8; i++) s += __expf(t[i] - mx);
    for (int o = 32; o; o >>= 1) s += __shfl_xor(s, o);
    if (!lane) reds[w] = s;
    __syncthreads();
    if (!tid) {
        rmax[bh * 64 + n] = mx;
        rsum[bh * 64 + n] = reds[0] + reds[1] + reds[2] + reds[3];
    }
}

// ---------------------------------------------------------------------------
// cross stage C: wpr[bh][m]
// ---------------------------------------------------------------------------
__global__ __launch_bounds__(256)
void wpr_kernel(const bf16* __restrict__ kc, const float* __restrict__ s1,
                const float* __restrict__ rmax, const float* __restrict__ rsum,
                const float* __restrict__ dw, float* __restrict__ wpr)
{
    int bh = blockIdx.x, b = bh >> 4, h = bh & 15;
    int m = blockIdx.y * 256 + threadIdx.x;
    __shared__ float cf[64], cm[64];
    if (threadIdx.x < 64) {
        cf[threadIdx.x] = dw[threadIdx.x] / rsum[bh * 64 + threadIdx.x];
        cm[threadIdx.x] = rmax[bh * 64 + threadIdx.x];
    }
    __syncthreads();
    float s1v = s1[(long)bh * 2048 + m];
    const bf16* kcb = kc + (long)b * 2048 * 1024 + (long)h * 2048 + m;
    float acc = 0.f;
#pragma unroll 8
    for (int n = 0; n < 64; n++)
        acc += cf[n] * __expf(b2f(kcb[(long)n * 16 * 2048]) * s1v - cm[n]);
    wpr[(long)bh * 2048 + m] = acc;
}

// ---------------------------------------------------------------------------
// cross stage D: outs[b, d*16+h] = sum_m wpr[bh][m]*vc[b, d*16+h, m] + db
// ---------------------------------------------------------------------------
__global__ __launch_bounds__(256)
void cout_kernel(const bf16* __restrict__ vc, const float* __restrict__ wpr,
                 const float* __restrict__ db, float* __restrict__ outs)
{
    int bh = blockIdx.x >> 2, dg = blockIdx.x & 3;
    int b = bh >> 4, h = bh & 15;
    int tid = threadIdx.x, lane = tid & 63, w = tid >> 6;
    __shared__ float lwpr[2048];
#pragma unroll
    for (int i = 0; i < 8; i++) lwpr[tid + i * 256] = wpr[(long)bh * 2048 + tid + i * 256];
    __syncthreads();
#pragma unroll
    for (int dd = 0; dd < 4; dd++) {
        int d = dg * 16 + w * 4 + dd;
        int o = d * 16 + h;
        const bf16* vrow = vc + (long)b * 2048 * 1024 + (long)o * 2048;
        float acc = 0.f;
#pragma unroll
        for (int j = 0; j < 4; j++) {
            int m = j * 512 + lane * 8;
            short8 vv = *(const short8*)&vrow[m];
#pragma unroll
            for (int k = 0; k < 8; k++) {
                bf16 bb = __builtin_bit_cast(bf16, (unsigned short)vv[k]);
                acc += lwpr[m + k] * b2f(bb);
            }
        }
        for (int t2 = 32; t2; t2 >>= 1) acc += __shfl_xor(acc, t2);
        if (!lane) outs[b * 1024 + o] = acc + db[0];
    }
}

// ---------------------------------------------------------------------------
extern "C" void kernel_launch(void* const* d_in, const int* in_sizes, int n_in,
                              void* d_out, int out_size, void* d_ws, size_t ws_size,
                              hipStream_t stream)
{
    const float* tgt  = (const float*)d_in[0];
    const float* mem  = (const float*)d_in[1];
    const float* pos  = (const float*)d_in[2];
    const float* qp   = (const float*)d_in[3];
    const float* ipw  = (const float*)d_in[4];
    const float* ipb  = (const float*)d_in[5];
    const float* outw = (const float*)d_in[6];
    const float* outb = (const float*)d_in[7];
    const float* cqw  = (const float*)d_in[8];
    const float* cqb  = (const float*)d_in[9];
    const float* ckw  = (const float*)d_in[10];
    const float* ckb  = (const float*)d_in[11];
    const float* cvw  = (const float*)d_in[12];
    const float* cvb  = (const float*)d_in[13];
    const float* dww  = (const float*)d_in[14];
    const float* dwb  = (const float*)d_in[15];
    const float* l1w  = (const float*)d_in[16];
    const float* l1b  = (const float*)d_in[17];
    const float* l2w  = (const float*)d_in[18];
    const float* l2b  = (const float*)d_in[19];
    const float* n1g  = (const float*)d_in[20];
    const float* n1b  = (const float*)d_in[21];
    const float* n2g  = (const float*)d_in[22];
    const float* n2b  = (const float*)d_in[23];
    const float* n3g  = (const float*)d_in[24];
    const float* n3b  = (const float*)d_in[25];

    char* ws = (char*)d_ws;
    auto MB = [](long x) { return x << 20; };
    bf16* w_ip    = (bf16*)(ws + MB(0));    // 6 MB
    bf16* w_out   = (bf16*)(ws + MB(6));    // 2 MB
    bf16* w_ck    = (bf16*)(ws + MB(8));    // 2 MB
    bf16* w_cv    = (bf16*)(ws + MB(10));   // 2 MB
    bf16* w_l1    = (bf16*)(ws + MB(12));   // 4 MB
    bf16* w_l2    = (bf16*)(ws + MB(16));   // 4 MB
    bf16* qkin    = (bf16*)(ws + MB(20));   // 4 MB
    bf16* tgtb    = (bf16*)(ws + MB(24));   // 4 MB
    bf16* memposb = (bf16*)(ws + MB(28));   // 16 MB
    bf16* memb    = (bf16*)(ws + MB(44));   // 16 MB
    bf16* qkbuf   = (bf16*)(ws + MB(60));   // 8 MB
    bf16* vtb     = (bf16*)(ws + MB(68));   // 4 MB
    bf16* kcb     = (bf16*)(ws + MB(72));   // 16 MB
    bf16* ctxb    = (bf16*)(ws + MB(104));  // 4 MB
    bf16* atmpb   = (bf16*)(ws + MB(108));  // 4 MB (LN1 input, bf16)
    float* s1buf  = (float*)(ws + MB(108)); // 512 KB (reuses slot after LN1)
    float* wprbuf = (float*)(ws + MB(109)); // 512 KB
    float* rmax   = (float*)(ws + MB(110));              // 16 KB
    float* rsum   = (float*)(ws + MB(110) + (64 << 10)); // 16 KB
    float* part   = (float*)(ws + MB(111)); // 256 KB
    float* tgt1   = (float*)(ws + MB(116)); // 8 MB
    float* asum   = (float*)(ws + MB(124)); // 16 KB
    float* qsum   = (float*)(ws + MB(125)); // 16 KB
    bf16* vcb     = (bf16*)(ws + MB(126));  // 16 MB
    float* outs   = (float*)(ws + MB(142)); // 16 KB
    float* tgt2   = (float*)(ws + MB(143)); // 8 MB
    bf16* tgt2b   = (bf16*)(ws + MB(151));  // 4 MB
    bf16* ff1b    = (bf16*)(ws + MB(155));  // 8 MB
    bf16* ff2b    = (bf16*)(ws + MB(163));  // 4 MB

    const int BIGZ = 1000000, BIGN = 1 << 30;

    // --- early prepass: only what qkv needs (ipw + tgt/qp) ---
    Cvt2Args ca{};
    ca.s[0] = {ipw,  nullptr, w_ip,    nullptr, 1536};
    ca.s[1] = {tgt,  qp,      qkin,    tgtb,    1024};
    cvt_kernel<<<dim3(2048, 1, 1), 256, 0, stream>>>(ca);

    // --- fused qkv projection: [2048,1024]x[1024,3072] (768 blocks) ---
    gemm_nt<64, 128><<<dim3(768, 1, 1), 256, 0, stream>>>(
        qkin, w_ip, nullptr, qkbuf, ipb,
        tgtb, nullptr, vtb, nullptr,
        32, 24,
        1024, 1024, 1024, 2048,
        0, 0, 0, 0, 0, 0, 1, BIGZ, 2048, 1.f, 1, 3);

    // --- hybrid: flash self-attention (256 blocks) + deferred conversions
    //     (512 blocks: outw/ckw/cvw/l1w/l2w/mem+pos; nblk in 4096-fl units) ---
    Cvt2Args cd{};
    cd.s[0] = {outw, nullptr, w_out,   nullptr, 256};
    cd.s[1] = {ckw,  nullptr, w_ck,    nullptr, 256};
    cd.s[2] = {cvw,  nullptr, w_cv,    nullptr, 256};
    cd.s[3] = {l1w,  nullptr, w_l1,    nullptr, 512};
    cd.s[4] = {l2w,  nullptr, w_l2,    nullptr, 512};
    cd.s[5] = {mem,  pos,     memposb, memb,    2048};
    flash_cvt<<<dim3(768, 1, 1), 512, 0, stream>>>(qkbuf, vtb, ctxb, cd);

    // --- out projection -> atmpb bf16 ---
    gemm_nt<64, 128><<<dim3(256, 1, 1), 256, 0, stream>>>(
        ctxb, w_out, nullptr, atmpb, outb,
        nullptr, nullptr, nullptr, nullptr,
        32, 8,
        1024, 1024, 1024, 1024,
        0, 0, 0, 0, 0, 0, 1, BIGZ, BIGN, 1.f, 1, 1);

    // --- LN1: tgt1 = LN(bf16(atmp) + tgt) ---
    ln_kernel<<<dim3(2048, 1, 1), 256, 0, stream>>>(
        nullptr, atmpb, tgt, nullptr, n1g, n1b, tgt1, nullptr);

    // --- qc path ---
    asum_part_kernel<<<dim3(256, 1, 1), 256, 0, stream>>>(tgt1, qp, part);
    asum_reduce_kernel<<<dim3(16, 1, 1), 256, 0, stream>>>(part, asum);
    qsum_kernel<<<dim3(256, 1, 1), 256, 0, stream>>>(cqw, cqb, asum, qsum);

    // --- fused kc+vc: 256x256 tile, BK=64 (256 blocks x 512 thr) ---
    kcvc_gemm<<<dim3(256, 1, 1), 512, 0, stream>>>(
        w_ck, w_cv, memposb, memb, kcb, vcb, ckb, cvb);

    // --- cross attention stages ---
    s1_kernel<<<dim3(64, 8, 1), 256, 0, stream>>>(kcb, qsum, s1buf);
    bsum_kernel<<<dim3(4096, 1, 1), 256, 0, stream>>>(kcb, s1buf, rmax, rsum);
    wpr_kernel<<<dim3(64, 8, 1), 256, 0, stream>>>(kcb, s1buf, rmax, rsum, dww, wprbuf);
    cout_kernel<<<dim3(256, 1, 1), 256, 0, stream>>>(vcb, wprbuf, dwb, outs);

    // --- LN2 ---
    ln_kernel<<<dim3(2048, 1, 1), 256, 0, stream>>>(
        tgt1, nullptr, nullptr, outs, n2g, n2b, tgt2, tgt2b);

    // --- FFN ---
    gemm_nt<64, 128><<<dim3(512, 1, 1), 256, 0, stream>>>(
        tgt2b, w_l1, nullptr, ff1b, l1b,
        nullptr, nullptr, nullptr, nullptr,
        32, 16,
        1024, 1024, 1024, 2048,
        0, 0, 0, 0, 0, 0, 1, BIGZ, BIGN, 1.f, 2, 2);

    gemm_nt<64, 128><<<dim3(256, 1, 1), 256, 0, stream>>>(
        ff1b, w_l2, nullptr, ff2b, l2b,
        nullptr, nullptr, nullptr, nullptr,
        32, 8,
        2048, 2048, 2048, 1024,
        0, 0, 0, 0, 0, 0, 1, BIGZ, BIGN, 1.f, 1, 1);

    // --- LN3 -> d_out ---
    ln_kernel<<<dim3(2048, 1, 1), 256, 0, stream>>>(
        nullptr, ff2b, tgt2, nullptr, n3g, n3b, (float*)d_out, nullptr);
}

// Round 20
// 246.445 us; speedup vs baseline: 1.2635x; 1.0117x over previous
//
#include <hip/hip_runtime.h>
#include <hip/hip_bf16.h>

typedef __hip_bfloat16 bf16;
typedef short short8 __attribute__((ext_vector_type(8)));
typedef float f32x4 __attribute__((ext_vector_type(4)));

#define Lq 512
#define Sm 2048
#define Bb 4
#define Ee 1024
#define Hh 16
#define FFd 2048
#define HDd 64

static __device__ __forceinline__ float b2f(bf16 x) { return __bfloat162float(x); }
static __device__ __forceinline__ bf16 f2b(float x) { return __float2bfloat16(x); }
static __device__ __forceinline__ unsigned short bits(bf16 x) {
    return __builtin_bit_cast(unsigned short, x);
}
static __device__ __forceinline__ float us2f(unsigned short u) {
    return b2f(__builtin_bit_cast(bf16, u));
}

static __device__ __forceinline__ void gload16(const void* g, void* l) {
    __builtin_amdgcn_global_load_lds(
        (const __attribute__((address_space(1))) unsigned int*)g,
        (__attribute__((address_space(3))) unsigned int*)l, 16, 0, 0);
}

static __device__ __forceinline__ short8 pack8(float4 a0, float4 a1) {
    short8 u;
    u[0] = (short)bits(f2b(a0.x)); u[1] = (short)bits(f2b(a0.y));
    u[2] = (short)bits(f2b(a0.z)); u[3] = (short)bits(f2b(a0.w));
    u[4] = (short)bits(f2b(a1.x)); u[5] = (short)bits(f2b(a1.y));
    u[6] = (short)bits(f2b(a1.z)); u[7] = (short)bits(f2b(a1.w));
    return u;
}

struct Cvt2Seg { const float* a; const float* b; bf16* d; bf16* d2; int nblk; };
struct Cvt2Args { Cvt2Seg s[8]; };

// ---------------------------------------------------------------------------
// kc+vc GEMM, 256x256 tile, BK=64, 2 LDS buffers (R14 configuration).
// T5 setprio REMOVED: 1 block/CU, 8 lockstep waves = no role diversity;
// m190 measured setprio harmful in exactly this regime. (A/B vs R18.)
// ---------------------------------------------------------------------------
__global__ __launch_bounds__(512, 2)
void kcvc_gemm(const bf16* __restrict__ wk, const bf16* __restrict__ wv,
               const bf16* __restrict__ mp, const bf16* __restrict__ mo,
               bf16* __restrict__ kc, bf16* __restrict__ vc,
               const float* __restrict__ kb, const float* __restrict__ vb)
{
    constexpr int BK = 64;
    __shared__ bf16 lA[2][256 * BK];
    __shared__ bf16 lB[2][256 * BK];

    const int tid  = threadIdx.x;
    const int lane = tid & 63;
    const int wm = (tid >> 6) >> 2;
    const int wn = (tid >> 6) & 3;

    int bid = (blockIdx.x & 7) * 32 + (blockIdx.x >> 3);
    const int bx = bid & 3;
    const int by = (bid >> 2) & 7;
    const int z  = bid >> 5;

    const bool isv = z >= 4;
    const int  b   = isv ? z - 4 : z;
    const bf16*  A    = isv ? wv : wk;
    const bf16*  B    = (isv ? mo : mp) + b * 1024;
    bf16*        C    = (isv ? vc : kc) + (long)b * 2097152;
    const float* bias = isv ? vb : kb;

    const int m0 = bx * 256, n0 = by * 256;
    const bf16* Abase = A + (long)m0 * 1024;
    const bf16* Bbase = B + (long)n0 * 4096;

    const int kgrp = lane >> 4, l16 = lane & 15;
    const int rsw = l16 & 7;

    auto stage = [&](int buf, int k0) {
#pragma unroll
        for (int r = 0; r < 4; r++) {
            int c = r * 512 + tid;
            int row = c >> 3;
            int ss = (c & 7) ^ (row & 7);
            gload16(Abase + (long)row * 1024 + k0 + ss * 8, &lA[buf][c * 8]);
        }
#pragma unroll
        for (int r = 0; r < 4; r++) {
            int c = r * 512 + tid;
            int row = c >> 3;
            int ss = (c & 7) ^ (row & 7);
            gload16(Bbase + (long)row * 4096 + k0 + ss * 8, &lB[buf][c * 8]);
        }
    };

    f32x4 acc[8][4];
#pragma unroll
    for (int i = 0; i < 8; i++)
#pragma unroll
        for (int j = 0; j < 4; j++) acc[i][j] = f32x4{0.f, 0.f, 0.f, 0.f};

    stage(0, 0);
    asm volatile("s_waitcnt vmcnt(0)" ::: "memory");
    __builtin_amdgcn_s_barrier();

    constexpr int NT = 16;
    for (int t = 0; t < NT; t++) {
        if (t + 1 < NT) stage((t + 1) & 1, (t + 1) * BK);

        const bf16* la = lA[t & 1];
        const bf16* lb = lB[t & 1];
#pragma unroll
        for (int h = 0; h < 2; h++) {
            const int sd = ((h * 4 + kgrp) ^ rsw) * 8;
            short8 af[8], bv[4];
#pragma unroll
            for (int i = 0; i < 8; i++)
                af[i] = *(const short8*)&la[(wm * 128 + i * 16 + l16) * BK + sd];
#pragma unroll
            for (int j = 0; j < 4; j++)
                bv[j] = *(const short8*)&lb[(wn * 64 + j * 16 + l16) * BK + sd];
#pragma unroll
            for (int i = 0; i < 8; i++)
#pragma unroll
                for (int j = 0; j < 4; j++)
                    acc[i][j] = __builtin_amdgcn_mfma_f32_16x16x32_bf16(af[i], bv[j], acc[i][j], 0, 0, 0);
        }

        asm volatile("s_waitcnt vmcnt(0)" ::: "memory");
        __builtin_amdgcn_s_barrier();
    }

#pragma unroll
    for (int i = 0; i < 8; i++) {
#pragma unroll
        for (int j = 0; j < 4; j++) {
#pragma unroll
            for (int r = 0; r < 4; r++) {
                int row = m0 + wm * 128 + i * 16 + kgrp * 4 + r;
                int col = n0 + wn * 64 + j * 16 + l16;
                float v = acc[i][j][r] + bias[row];
                float v2 = __shfl_xor(v, 1);
                if (!(l16 & 1)) {
                    unsigned int pk = (unsigned int)bits(f2b(v)) |
                                      ((unsigned int)bits(f2b(v2)) << 16);
                    *(unsigned int*)&C[(long)row * 2048 + col] = pk;
                }
            }
        }
    }
}

// ---------------------------------------------------------------------------
// HYBRID: flash self-attention (blocks 0..255) + deferred f32->bf16
// conversions (blocks 256..767, grid-stride; 4096 floats/chunk). R18 winner.
// ---------------------------------------------------------------------------
__global__ __launch_bounds__(512, 2)
void flash_cvt(const bf16* __restrict__ qk, const bf16* __restrict__ vt,
               bf16* __restrict__ ctx, Cvt2Args args)
{
    __shared__ bf16 lQ[128 * 64];
    __shared__ bf16 lK[2][64 * 64];
    __shared__ bf16 lV[2][64 * 64];
    __shared__ bf16 lP[128 * 64];
    __shared__ float scb[128];

    if (blockIdx.x >= 256) {
        const int cb = blockIdx.x - 256;       // 0..511
        for (int ci = cb; ci < 3840; ci += 512) {
            int rem = ci;
            int si = 0;
            while (si < 5 && rem >= args.s[si].nblk) { rem -= args.s[si].nblk; si++; }
            Cvt2Seg sg = args.s[si];
            const long i = (long)rem * 4096 + threadIdx.x * 8;

            float4 a0 = *(const float4*)(sg.a + i);
            float4 a1 = *(const float4*)(sg.a + i + 4);
            float4 s0 = a0, s1 = a1;
            if (sg.b) {
                float4 b0 = *(const float4*)(sg.b + i);
                float4 b1 = *(const float4*)(sg.b + i + 4);
                s0.x += b0.x; s0.y += b0.y; s0.z += b0.z; s0.w += b0.w;
                s1.x += b1.x; s1.y += b1.y; s1.z += b1.z; s1.w += b1.w;
            }
            *(short8*)((unsigned short*)sg.d + i) = pack8(s0, s1);
            if (sg.d2) {
                *(short8*)((unsigned short*)sg.d2 + i) = pack8(a0, a1);
            }
        }
        return;
    }

    const int tid  = threadIdx.x;
    const int lane = tid & 63;
    const int wq   = tid >> 6;
    const int kgrp = lane >> 4, l16 = lane & 15;

    const int qt = blockIdx.x & 3;
    const int bh = blockIdx.x >> 2;
    const int b = bh >> 4, h = bh & 15;
    const int L0 = qt * 128;

#pragma unroll
    for (int it = 0; it < 2; it++) {
        int c = it * 512 + tid;
        int rr = c >> 3, sl = c & 7, ss = sl ^ (rr & 7);
        gload16(qk + ((long)(L0 + rr) * 4 + b) * 2048 + h * 64 + ss * 8,
                &lQ[(it * 512 + wq * 64) * 8]);
    }

    auto stageKV = [&](int buf, int st) {
        int rr = tid >> 3, sl = tid & 7, ss = sl ^ (rr & 7);
        gload16(qk + ((long)(st * 64 + rr) * 4 + b) * 2048 + 1024 + h * 64 + ss * 8,
                &lK[buf][(wq * 64) * 8]);
        gload16(vt + ((long)(b * 1024 + h * 64 + rr)) * 512 + st * 64 + ss * 8,
                &lV[buf][(wq * 64) * 8]);
    };

    auto frag = [&](const bf16* base, int row, int kk) {
        return *(const short8*)&base[row * 64 + (((kk * 4 + kgrp) ^ (l16 & 7)) * 8)];
    };

    f32x4 acc_o[4];
#pragma unroll
    for (int j = 0; j < 4; j++) acc_o[j] = f32x4{0.f, 0.f, 0.f, 0.f};
    float m_run = -1e30f, l_run = 0.f;

    stageKV(0, 0);
    asm volatile("s_waitcnt vmcnt(0)" ::: "memory");
    __builtin_amdgcn_s_barrier();

    int buf = 0;
    for (int st = 0; st < 8; st++) {
        if (st < 7) stageKV(buf ^ 1, st + 1);

        f32x4 accs[4];
#pragma unroll
        for (int fm = 0; fm < 4; fm++) accs[fm] = f32x4{0.f, 0.f, 0.f, 0.f};
        __builtin_amdgcn_s_setprio(1);
#pragma unroll
        for (int kk = 0; kk < 2; kk++) {
            short8 bq = frag(lQ, wq * 16 + l16, kk);
#pragma unroll
            for (int fm = 0; fm < 4; fm++) {
                short8 af = frag(lK[buf], fm * 16 + l16, kk);
                accs[fm] = __builtin_amdgcn_mfma_f32_16x16x32_bf16(af, bq, accs[fm], 0, 0, 0);
            }
        }
        __builtin_amdgcn_s_setprio(0);

        float v[4][4], p[4][4];
        float tmax = -1e30f;
#pragma unroll
        for (int fm = 0; fm < 4; fm++)
#pragma unroll
            for (int r = 0; r < 4; r++) {
                v[fm][r] = accs[fm][r] * 0.125f;
                tmax = fmaxf(tmax, v[fm][r]);
            }
        tmax = fmaxf(tmax, __shfl_xor(tmax, 16));
        tmax = fmaxf(tmax, __shfl_xor(tmax, 32));
        float m_new = fmaxf(m_run, tmax);
        float sc = __expf(m_run - m_new);
        float sum = 0.f;
#pragma unroll
        for (int fm = 0; fm < 4; fm++)
#pragma unroll
            for (int r = 0; r < 4; r++) {
                p[fm][r] = __expf(v[fm][r] - m_new);
                sum += p[fm][r];
            }
        sum += __shfl_xor(sum, 16);
        sum += __shfl_xor(sum, 32);
        l_run = l_run * sc + sum;
        m_run = m_new;

        if (!kgrp) scb[wq * 16 + l16] = sc;
        asm volatile("s_waitcnt lgkmcnt(0)" ::: "memory");
        __builtin_amdgcn_sched_barrier(0);
        float sc2[4];
#pragma unroll
        for (int r = 0; r < 4; r++) sc2[r] = scb[wq * 16 + kgrp * 4 + r];
#pragma unroll
        for (int fn = 0; fn < 4; fn++)
#pragma unroll
            for (int r = 0; r < 4; r++) acc_o[fn][r] *= sc2[r];

#pragma unroll
        for (int fm = 0; fm < 4; fm++) {
            int l = wq * 16 + l16;
            int sp = (fm * 2 + (kgrp >> 1)) ^ (l16 & 7);
            uint2 pk;
            pk.x = (unsigned int)bits(f2b(p[fm][0])) | ((unsigned int)bits(f2b(p[fm][1])) << 16);
            pk.y = (unsigned int)bits(f2b(p[fm][2])) | ((unsigned int)bits(f2b(p[fm][3])) << 16);
            *(uint2*)&lP[l * 64 + sp * 8 + (kgrp & 1) * 4] = pk;
        }
        asm volatile("s_waitcnt lgkmcnt(0)" ::: "memory");
        __builtin_amdgcn_sched_barrier(0);

        __builtin_amdgcn_s_setprio(1);
#pragma unroll
        for (int kk = 0; kk < 2; kk++) {
            short8 ap = frag(lP, wq * 16 + l16, kk);
#pragma unroll
            for (int fn = 0; fn < 4; fn++) {
                short8 bvf = frag(lV[buf], fn * 16 + l16, kk);
                acc_o[fn] = __builtin_amdgcn_mfma_f32_16x16x32_bf16(ap, bvf, acc_o[fn], 0, 0, 0);
            }
        }
        __builtin_amdgcn_s_setprio(0);

        asm volatile("s_waitcnt vmcnt(0)" ::: "memory");
        __builtin_amdgcn_s_barrier();
        buf ^= 1;
    }

    if (!kgrp) scb[wq * 16 + l16] = 1.f / l_run;
    asm volatile("s_waitcnt lgkmcnt(0)" ::: "memory");
    __builtin_amdgcn_sched_barrier(0);
    float inv[4];
#pragma unroll
    for (int r = 0; r < 4; r++) inv[r] = scb[wq * 16 + kgrp * 4 + r];
#pragma unroll
    for (int fn = 0; fn < 4; fn++) {
#pragma unroll
        for (int r = 0; r < 4; r++) {
            int lg = L0 + wq * 16 + kgrp * 4 + r;
            int d  = fn * 16 + l16;
            float vv = acc_o[fn][r] * inv[r];
            float v2 = __shfl_xor(vv, 1);
            if (!(l16 & 1)) {
                unsigned int pk = (unsigned int)bits(f2b(vv)) |
                                  ((unsigned int)bits(f2b(v2)) << 16);
                *(unsigned int*)&ctx[((long)lg * 4 + b) * 1024 + h * 64 + d] = pk;
            }
        }
    }
}

// ---------------------------------------------------------------------------
// NT bf16 MFMA GEMM — BK=64 / 2-buffer / h-split (unchanged; keeps T5:
// 2-3 blocks/CU give the role diversity T5 needs).
// ---------------------------------------------------------------------------
template<int BM, int BN>
__global__ __launch_bounds__(256)
void gemm_nt(const bf16* __restrict__ A, const bf16* __restrict__ Bw,
             float* __restrict__ Cf, bf16* __restrict__ Cb,
             const float* __restrict__ bias,
             const bf16* __restrict__ A2, const bf16* __restrict__ B2,
             bf16* __restrict__ Cb2, const float* __restrict__ bias2,
             int gx, int gy,
             int K, long lda, long ldb, long ldc,
             long sA1, long sA2, long sB1, long sB2, long sC1, long sC2,
             int zdiv, int zsplit, int nsplit, float alpha, int mode, int mode2)
{
    constexpr int BK = 64;
    constexpr int RA = BM / 32, RB = BN / 32;
    __shared__ bf16 lA[2][BM * BK];
    __shared__ bf16 lB[2][BN * BK];

    const int tid  = threadIdx.x;
    const int lane = tid & 63;
    const int wave = tid >> 6;
    const int wm = wave >> 1, wn = wave & 1;
    constexpr int RM = BM / 2, RN = BN / 2;
    constexpr int FM = RM / 16, FN = RN / 16;

    const int nwg = gridDim.x;
    const int cpx = nwg >> 3;
    int bid = (blockIdx.x & 7) * cpx + (blockIdx.x >> 3);
    const int bx = bid % gx;
    int tmp = bid / gx;
    const int by = tmp % gy;
    const int z  = tmp / gy;

    const int m0 = bx * BM;
    const int n0 = by * BN;

    const bool use2 = (z >= zsplit) || (n0 >= nsplit);
    const int  zz   = (z >= zsplit) ? z - zsplit : z;
    const bf16*  Ap = (use2 && A2)    ? A2    : A;
    const bf16*  Bp = (use2 && B2)    ? B2    : Bw;
    const float* bp = (use2 && bias2) ? bias2 : bias;
    const int    md = use2 ? mode2 : mode;
    bf16*        Co = (use2 && Cb2)   ? Cb2   : Cb;

    const long offA = (long)(zz / zdiv) * sA1 + (long)(zz % zdiv) * sA2;
    const long offB = (long)(zz / zdiv) * sB1 + (long)(zz % zdiv) * sB2;
    const long offC = (long)(zz / zdiv) * sC1 + (long)(zz % zdiv) * sC2;

    const bf16* Abase = Ap + offA + (long)m0 * lda;
    const bf16* Bbase = Bp + offB + (long)n0 * ldb;

    const int kgrp = lane >> 4;
    const int l16  = lane & 15;
    const int rsw  = l16 & 7;

    auto stage = [&](int buf, int k0) {
#pragma unroll
        for (int r = 0; r < RA; r++) {
            int c = r * 256 + tid;
            int row = c >> 3;
            int ss = (c & 7) ^ (row & 7);
            gload16(Abase + (long)row * lda + k0 + ss * 8, &lA[buf][c * 8]);
        }
#pragma unroll
        for (int r = 0; r < RB; r++) {
            int c = r * 256 + tid;
            int row = c >> 3;
            int ss = (c & 7) ^ (row & 7);
            gload16(Bbase + (long)row * ldb + k0 + ss * 8, &lB[buf][c * 8]);
        }
    };

    f32x4 acc[FM][FN];
#pragma unroll
    for (int i = 0; i < FM; i++)
#pragma unroll
        for (int j = 0; j < FN; j++) acc[i][j] = f32x4{0.f, 0.f, 0.f, 0.f};

    const int nt = K / BK;
    stage(0, 0);
    asm volatile("s_waitcnt vmcnt(0)" ::: "memory");
    __builtin_amdgcn_s_barrier();

    for (int t = 0; t < nt; t++) {
        if (t + 1 < nt) stage((t + 1) & 1, (t + 1) * BK);

        const bf16* la = lA[t & 1];
        const bf16* lb = lB[t & 1];
#pragma unroll
        for (int h = 0; h < 2; h++) {
            const int sd = ((h * 4 + kgrp) ^ rsw) * 8;
            short8 af[FM], bv[FN];
#pragma unroll
            for (int i = 0; i < FM; i++)
                af[i] = *(const short8*)&la[(wm * RM + i * 16 + l16) * BK + sd];
#pragma unroll
            for (int j = 0; j < FN; j++)
                bv[j] = *(const short8*)&lb[(wn * RN + j * 16 + l16) * BK + sd];
            __builtin_amdgcn_s_setprio(1);
#pragma unroll
            for (int i = 0; i < FM; i++)
#pragma unroll
                for (int j = 0; j < FN; j++)
                    acc[i][j] = __builtin_amdgcn_mfma_f32_16x16x32_bf16(af[i], bv[j], acc[i][j], 0, 0, 0);
            __builtin_amdgcn_s_setprio(0);
        }

        asm volatile("s_waitcnt vmcnt(0)" ::: "memory");
        __builtin_amdgcn_s_barrier();
    }

#pragma unroll
    for (int i = 0; i < FM; i++) {
#pragma unroll
        for (int j = 0; j < FN; j++) {
#pragma unroll
            for (int r = 0; r < 4; r++) {
                int row = m0 + wm * RM + i * 16 + kgrp * 4 + r;
                int col = n0 + wn * RN + j * 16 + l16;
                float v = alpha * acc[i][j][r] + (bp ? bp[col] : 0.f);
                float v2 = __shfl_xor(v, 1);
                if (md == 0) {
                    if (!(l16 & 1)) {
                        float2 pv = {v, v2};
                        *(float2*)&Cf[offC + (long)row * ldc + col] = pv;
                    }
                } else if (md == 1) {
                    if (!(l16 & 1)) {
                        unsigned int pk = (unsigned int)bits(f2b(v)) |
                                          ((unsigned int)bits(f2b(v2)) << 16);
                        *(unsigned int*)&Co[offC + (long)row * ldc + col] = pk;
                    }
                } else if (md == 2) {
                    if (!(l16 & 1)) {
                        unsigned int pk = (unsigned int)bits(f2b(fmaxf(v, 0.f))) |
                                          ((unsigned int)bits(f2b(fmaxf(v2, 0.f))) << 16);
                        *(unsigned int*)&Co[offC + (long)row * ldc + col] = pk;
                    }
                } else {
                    int o = col - nsplit;
                    Cb2[((long)(row & 3) * 1024 + o) * 512 + (row >> 2)] = f2b(v);
                }
            }
        }
    }
}

// ---------------------------------------------------------------------------
// f32->bf16 convert prepass — EARLY segments only (ipw + tgt/qp).
// ---------------------------------------------------------------------------
__global__ __launch_bounds__(256)
void cvt_kernel(Cvt2Args args)
{
    for (int ci = blockIdx.x; ci < 2560; ci += 2048) {
        int rem = ci;
        int si = 0;
        while (si < 7 && rem >= args.s[si].nblk) { rem -= args.s[si].nblk; si++; }
        Cvt2Seg sg = args.s[si];
        const long i = (long)rem * 2048 + threadIdx.x * 8;

        float4 a0 = *(const float4*)(sg.a + i);
        float4 a1 = *(const float4*)(sg.a + i + 4);
        float4 s0 = a0, s1 = a1;
        if (sg.b) {
            float4 b0 = *(const float4*)(sg.b + i);
            float4 b1 = *(const float4*)(sg.b + i + 4);
            s0.x += b0.x; s0.y += b0.y; s0.z += b0.z; s0.w += b0.w;
            s1.x += b1.x; s1.y += b1.y; s1.z += b1.z; s1.w += b1.w;
        }
        *(short8*)((unsigned short*)sg.d + i) = pack8(s0, s1);
        if (sg.d2) {
            *(short8*)((unsigned short*)sg.d2 + i) = pack8(a0, a1);
        }
    }
}

// ---------------------------------------------------------------------------
// LayerNorm over E=1024: input x (f32) OR xB (bf16); + res (f32) / resb.
// ---------------------------------------------------------------------------
__global__ __launch_bounds__(256)
void ln_kernel(const float* __restrict__ x, const bf16* __restrict__ xB,
               const float* __restrict__ res, const float* __restrict__ resb,
               const float* __restrict__ g, const float* __restrict__ be,
               float* __restrict__ outF, bf16* __restrict__ outB)
{
    long row = blockIdx.x;
    int tid = threadIdx.x, lane = tid & 63, w = tid >> 6;
    float vv[4];
    if (x) {
        float4 xv = *(const float4*)(x + row * 1024 + tid * 4);
        vv[0] = xv.x; vv[1] = xv.y; vv[2] = xv.z; vv[3] = xv.w;
    } else {
        ushort4 xv = *(const ushort4*)((const unsigned short*)xB + row * 1024 + tid * 4);
        vv[0] = us2f(xv.x); vv[1] = us2f(xv.y); vv[2] = us2f(xv.z); vv[3] = us2f(xv.w);
    }
    if (res) {
        float4 rv = *(const float4*)(res + row * 1024 + tid * 4);
        vv[0] += rv.x; vv[1] += rv.y; vv[2] += rv.z; vv[3] += rv.w;
    }
    if (resb) {
        float4 rv = *(const float4*)(resb + (row & 3) * 1024 + tid * 4);
        vv[0] += rv.x; vv[1] += rv.y; vv[2] += rv.z; vv[3] += rv.w;
    }
    float s = vv[0] + vv[1] + vv[2] + vv[3];
    float q = vv[0] * vv[0] + vv[1] * vv[1] + vv[2] * vv[2] + vv[3] * vv[3];
    __shared__ float rs[4], rq[4];
    for (int o = 32; o; o >>= 1) { s += __shfl_xor(s, o); q += __shfl_xor(q, o); }
    if (!lane) { rs[w] = s; rq[w] = q; }
    __syncthreads();
    s = rs[0] + rs[1] + rs[2] + rs[3];
    q = rq[0] + rq[1] + rq[2] + rq[3];
    float mean = s * (1.f / 1024.f);
    float var  = q * (1.f / 1024.f) - mean * mean;
    float rstd = rsqrtf(var + 1e-5f);
    float4 gv = *(const float4*)(g + tid * 4);
    float4 bv = *(const float4*)(be + tid * 4);
    float o0 = (vv[0] - mean) * rstd * gv.x + bv.x;
    float o1 = (vv[1] - mean) * rstd * gv.y + bv.y;
    float o2 = (vv[2] - mean) * rstd * gv.z + bv.z;
    float o3 = (vv[3] - mean) * rstd * gv.w + bv.w;
    if (outF) {
        float4 ov = {o0, o1, o2, o3};
        *(float4*)(outF + row * 1024 + tid * 4) = ov;
    }
    if (outB) {
        ushort4 u;
        u.x = bits(f2b(o0)); u.y = bits(f2b(o1));
        u.z = bits(f2b(o2)); u.w = bits(f2b(o3));
        *reinterpret_cast<ushort4*>((unsigned short*)outB + row * 1024 + tid * 4) = u;
    }
}

// ---------------------------------------------------------------------------
// asum partials over L, then reduce
// ---------------------------------------------------------------------------
__global__ __launch_bounds__(256)
void asum_part_kernel(const float* __restrict__ t1, const float* __restrict__ qp,
                      float* __restrict__ part)
{
    int blk = blockIdx.x;
    int lc = blk >> 4, b = (blk >> 2) & 3, ec = blk & 3;
    int e = ec * 256 + threadIdx.x;
    float acc = 0.f;
#pragma unroll 4
    for (int l = lc * 32; l < lc * 32 + 32; l++) {
        long idx = ((long)(l * 4 + b)) * 1024 + e;
        acc += t1[idx] + qp[idx];
    }
    part[(lc * 4 + b) * 1024 + e] = acc;
}

__global__ __launch_bounds__(256)
void asum_reduce_kernel(const float* __restrict__ part, float* __restrict__ asum)
{
    int b = blockIdx.x >> 2, ec = blockIdx.x & 3;
    int e = ec * 256 + threadIdx.x;
    float acc = 0.f;
#pragma unroll
    for (int lc = 0; lc < 16; lc++) acc += part[(lc * 4 + b) * 1024 + e];
    asum[b * 1024 + e] = acc;
}

// ---------------------------------------------------------------------------
// qsum[b,o] = sum_e cq_w[o,e]*asum[b,e] + 512*cq_b[o]
// ---------------------------------------------------------------------------
__global__ __launch_bounds__(256)
void qsum_kernel(const float* __restrict__ cqw, const float* __restrict__ cqb,
                 const float* __restrict__ asum, float* __restrict__ qsum)
{
    int o = blockIdx.x * 4 + (threadIdx.x >> 6);
    int lane = threadIdx.x & 63;
    float a0 = 0, a1 = 0, a2 = 0, a3 = 0;
    for (int j = 0; j < 16; j++) {
        int e = lane + j * 64;
        float wv = cqw[(long)o * 1024 + e];
        a0 += wv * asum[e];
        a1 += wv * asum[1024 + e];
        a2 += wv * asum[2048 + e];
        a3 += wv * asum[3072 + e];
    }
    for (int t = 32; t; t >>= 1) {
        a0 += __shfl_xor(a0, t); a1 += __shfl_xor(a1, t);
        a2 += __shfl_xor(a2, t); a3 += __shfl_xor(a3, t);
    }
    if (!lane) {
        float bb = 512.f * cqb[o];
        qsum[o] = a0 + bb; qsum[1024 + o] = a1 + bb;
        qsum[2048 + o] = a2 + bb; qsum[3072 + o] = a3 + bb;
    }
}

// ---------------------------------------------------------------------------
// cross stage A: s1[bh][m]
// ---------------------------------------------------------------------------
__global__ __launch_bounds__(256)
void s1_kernel(const bf16* __restrict__ kc, const float* __restrict__ qsum,
               float* __restrict__ s1)
{
    int bh = blockIdx.x, b = bh >> 4, h = bh & 15;
    int m = blockIdx.y * 256 + threadIdx.x;
    __shared__ float qd[64];
    if (threadIdx.x < 64) qd[threadIdx.x] = qsum[b * 1024 + threadIdx.x * 16 + h];
    __syncthreads();
    const bf16* kcb = kc + (long)b * 2048 * 1024 + (long)h * 2048 + m;
    float acc = 0.f;
#pragma unroll 8
    for (int d = 0; d < 64; d++) acc += qd[d] * b2f(kcb[(long)d * 16 * 2048]);
    s1[(long)bh * 2048 + m] = acc * 0.125f;
}

// ---------------------------------------------------------------------------
// cross stage B: per (b,h,n) row max & expsum
// ---------------------------------------------------------------------------
__global__ __launch_bounds__(256)
void bsum_kernel(const bf16* __restrict__ kc, const float* __restrict__ s1,
                 float* __restrict__ rmax, float* __restrict__ rsum)
{
    int bh = blockIdx.x >> 6, n = blockIdx.x & 63;
    int b = bh >> 4, h = bh & 15;
    int tid = threadIdx.x, lane = tid & 63, w = tid >> 6;
    const bf16* row = kc + (long)b * 2048 * 1024 + (long)(n * 16 + h) * 2048;
    const float* s1r = s1 + (long)bh * 2048;
    float t[8];
    float mx = -1e30f;
#pragma unroll
    for (int i = 0; i < 8; i++) {
        int m = tid + i * 256;
        t[i] = b2f(row[m]) * s1r[m];
        mx = fmaxf(mx, t[i]);
    }
    __shared__ float redm[4], reds[4];
    for (int o = 32; o; o >>= 1) mx = fmaxf(mx, __shfl_xor(mx, o));
    if (!lane) redm[w] = mx;
    __syncthreads();
    mx = fmaxf(fmaxf(redm[0], redm[1]), fmaxf(redm[2], redm[3]));
    float s = 0.f;
#pragma unroll
    for (int i = 0; i < 8; i++) s += __expf(t[i] - mx);
    for (int o = 32; o; o >>= 1) s += __shfl_xor(s, o);
    if (!lane) reds[w] = s;
    __syncthreads();
    if (!tid) {
        rmax[bh * 64 + n] = mx;
        rsum[bh * 64 + n] = reds[0] + reds[1] + reds[2] + reds[3];
    }
}

// ---------------------------------------------------------------------------
// cross stage C: wpr[bh][m]
// ---------------------------------------------------------------------------
__global__ __launch_bounds__(256)
void wpr_kernel(const bf16* __restrict__ kc, const float* __restrict__ s1,
                const float* __restrict__ rmax, const float* __restrict__ rsum,
                const float* __restrict__ dw, float* __restrict__ wpr)
{
    int bh = blockIdx.x, b = bh >> 4, h = bh & 15;
    int m = blockIdx.y * 256 + threadIdx.x;
    __shared__ float cf[64], cm[64];
    if (threadIdx.x < 64) {
        cf[threadIdx.x] = dw[threadIdx.x] / rsum[bh * 64 + threadIdx.x];
        cm[threadIdx.x] = rmax[bh * 64 + threadIdx.x];
    }
    __syncthreads();
    float s1v = s1[(long)bh * 2048 + m];
    const bf16* kcb = kc + (long)b * 2048 * 1024 + (long)h * 2048 + m;
    float acc = 0.f;
#pragma unroll 8
    for (int n = 0; n < 64; n++)
        acc += cf[n] * __expf(b2f(kcb[(long)n * 16 * 2048]) * s1v - cm[n]);
    wpr[(long)bh * 2048 + m] = acc;
}

// ---------------------------------------------------------------------------
// cross stage D: outs[b, d*16+h] = sum_m wpr[bh][m]*vc[b, d*16+h, m] + db
// ---------------------------------------------------------------------------
__global__ __launch_bounds__(256)
void cout_kernel(const bf16* __restrict__ vc, const float* __restrict__ wpr,
                 const float* __restrict__ db, float* __restrict__ outs)
{
    int bh = blockIdx.x >> 2, dg = blockIdx.x & 3;
    int b = bh >> 4, h = bh & 15;
    int tid = threadIdx.x, lane = tid & 63, w = tid >> 6;
    __shared__ float lwpr[2048];
#pragma unroll
    for (int i = 0; i < 8; i++) lwpr[tid + i * 256] = wpr[(long)bh * 2048 + tid + i * 256];
    __syncthreads();
#pragma unroll
    for (int dd = 0; dd < 4; dd++) {
        int d = dg * 16 + w * 4 + dd;
        int o = d * 16 + h;
        const bf16* vrow = vc + (long)b * 2048 * 1024 + (long)o * 2048;
        float acc = 0.f;
#pragma unroll
        for (int j = 0; j < 4; j++) {
            int m = j * 512 + lane * 8;
            short8 vv = *(const short8*)&vrow[m];
#pragma unroll
            for (int k = 0; k < 8; k++) {
                bf16 bb = __builtin_bit_cast(bf16, (unsigned short)vv[k]);
                acc += lwpr[m + k] * b2f(bb);
            }
        }
        for (int t2 = 32; t2; t2 >>= 1) acc += __shfl_xor(acc, t2);
        if (!lane) outs[b * 1024 + o] = acc + db[0];
    }
}

// ---------------------------------------------------------------------------
extern "C" void kernel_launch(void* const* d_in, const int* in_sizes, int n_in,
                              void* d_out, int out_size, void* d_ws, size_t ws_size,
                              hipStream_t stream)
{
    const float* tgt  = (const float*)d_in[0];
    const float* mem  = (const float*)d_in[1];
    const float* pos  = (const float*)d_in[2];
    const float* qp   = (const float*)d_in[3];
    const float* ipw  = (const float*)d_in[4];
    const float* ipb  = (const float*)d_in[5];
    const float* outw = (const float*)d_in[6];
    const float* outb = (const float*)d_in[7];
    const float* cqw  = (const float*)d_in[8];
    const float* cqb  = (const float*)d_in[9];
    const float* ckw  = (const float*)d_in[10];
    const float* ckb  = (const float*)d_in[11];
    const float* cvw  = (const float*)d_in[12];
    const float* cvb  = (const float*)d_in[13];
    const float* dww  = (const float*)d_in[14];
    const float* dwb  = (const float*)d_in[15];
    const float* l1w  = (const float*)d_in[16];
    const float* l1b  = (const float*)d_in[17];
    const float* l2w  = (const float*)d_in[18];
    const float* l2b  = (const float*)d_in[19];
    const float* n1g  = (const float*)d_in[20];
    const float* n1b  = (const float*)d_in[21];
    const float* n2g  = (const float*)d_in[22];
    const float* n2b  = (const float*)d_in[23];
    const float* n3g  = (const float*)d_in[24];
    const float* n3b  = (const float*)d_in[25];

    char* ws = (char*)d_ws;
    auto MB = [](long x) { return x << 20; };
    bf16* w_ip    = (bf16*)(ws + MB(0));    // 6 MB
    bf16* w_out   = (bf16*)(ws + MB(6));    // 2 MB
    bf16* w_ck    = (bf16*)(ws + MB(8));    // 2 MB
    bf16* w_cv    = (bf16*)(ws + MB(10));   // 2 MB
    bf16* w_l1    = (bf16*)(ws + MB(12));   // 4 MB
    bf16* w_l2    = (bf16*)(ws + MB(16));   // 4 MB
    bf16* qkin    = (bf16*)(ws + MB(20));   // 4 MB
    bf16* tgtb    = (bf16*)(ws + MB(24));   // 4 MB
    bf16* memposb = (bf16*)(ws + MB(28));   // 16 MB
    bf16* memb    = (bf16*)(ws + MB(44));   // 16 MB
    bf16* qkbuf   = (bf16*)(ws + MB(60));   // 8 MB
    bf16* vtb     = (bf16*)(ws + MB(68));   // 4 MB
    bf16* kcb     = (bf16*)(ws + MB(72));   // 16 MB
    bf16* ctxb    = (bf16*)(ws + MB(104));  // 4 MB
    bf16* atmpb   = (bf16*)(ws + MB(108));  // 4 MB (LN1 input, bf16)
    float* s1buf  = (float*)(ws + MB(108)); // 512 KB (reuses slot after LN1)
    float* wprbuf = (float*)(ws + MB(109)); // 512 KB
    float* rmax   = (float*)(ws + MB(110));              // 16 KB
    float* rsum   = (float*)(ws + MB(110) + (64 << 10)); // 16 KB
    float* part   = (float*)(ws + MB(111)); // 256 KB
    float* tgt1   = (float*)(ws + MB(116)); // 8 MB
    float* asum   = (float*)(ws + MB(124)); // 16 KB
    float* qsum   = (float*)(ws + MB(125)); // 16 KB
    bf16* vcb     = (bf16*)(ws + MB(126));  // 16 MB
    float* outs   = (float*)(ws + MB(142)); // 16 KB
    float* tgt2   = (float*)(ws + MB(143)); // 8 MB
    bf16* tgt2b   = (bf16*)(ws + MB(151));  // 4 MB
    bf16* ff1b    = (bf16*)(ws + MB(155));  // 8 MB
    bf16* ff2b    = (bf16*)(ws + MB(163));  // 4 MB

    const int BIGZ = 1000000, BIGN = 1 << 30;

    // --- early prepass: only what qkv needs (ipw + tgt/qp) ---
    Cvt2Args ca{};
    ca.s[0] = {ipw,  nullptr, w_ip,    nullptr, 1536};
    ca.s[1] = {tgt,  qp,      qkin,    tgtb,    1024};
    cvt_kernel<<<dim3(2048, 1, 1), 256, 0, stream>>>(ca);

    // --- fused qkv projection: [2048,1024]x[1024,3072] (768 blocks) ---
    gemm_nt<64, 128><<<dim3(768, 1, 1), 256, 0, stream>>>(
        qkin, w_ip, nullptr, qkbuf, ipb,
        tgtb, nullptr, vtb, nullptr,
        32, 24,
        1024, 1024, 1024, 2048,
        0, 0, 0, 0, 0, 0, 1, BIGZ, 2048, 1.f, 1, 3);

    // --- hybrid: flash self-attention (256 blocks) + deferred conversions ---
    Cvt2Args cd{};
    cd.s[0] = {outw, nullptr, w_out,   nullptr, 256};
    cd.s[1] = {ckw,  nullptr, w_ck,    nullptr, 256};
    cd.s[2] = {cvw,  nullptr, w_cv,    nullptr, 256};
    cd.s[3] = {l1w,  nullptr, w_l1,    nullptr, 512};
    cd.s[4] = {l2w,  nullptr, w_l2,    nullptr, 512};
    cd.s[5] = {mem,  pos,     memposb, memb,    2048};
    flash_cvt<<<dim3(768, 1, 1), 512, 0, stream>>>(qkbuf, vtb, ctxb, cd);

    // --- out projection -> atmpb bf16 ---
    gemm_nt<64, 128><<<dim3(256, 1, 1), 256, 0, stream>>>(
        ctxb, w_out, nullptr, atmpb, outb,
        nullptr, nullptr, nullptr, nullptr,
        32, 8,
        1024, 1024, 1024, 1024,
        0, 0, 0, 0, 0, 0, 1, BIGZ, BIGN, 1.f, 1, 1);

    // --- LN1: tgt1 = LN(bf16(atmp) + tgt) ---
    ln_kernel<<<dim3(2048, 1, 1), 256, 0, stream>>>(
        nullptr, atmpb, tgt, nullptr, n1g, n1b, tgt1, nullptr);

    // --- qc path ---
    asum_part_kernel<<<dim3(256, 1, 1), 256, 0, stream>>>(tgt1, qp, part);
    asum_reduce_kernel<<<dim3(16, 1, 1), 256, 0, stream>>>(part, asum);
    qsum_kernel<<<dim3(256, 1, 1), 256, 0, stream>>>(cqw, cqb, asum, qsum);

    // --- fused kc+vc: 256x256 tile, BK=64 (256 blocks x 512 thr) ---
    kcvc_gemm<<<dim3(256, 1, 1), 512, 0, stream>>>(
        w_ck, w_cv, memposb, memb, kcb, vcb, ckb, cvb);

    // --- cross attention stages ---
    s1_kernel<<<dim3(64, 8, 1), 256, 0, stream>>>(kcb, qsum, s1buf);
    bsum_kernel<<<dim3(4096, 1, 1), 256, 0, stream>>>(kcb, s1buf, rmax, rsum);
    wpr_kernel<<<dim3(64, 8, 1), 256, 0, stream>>>(kcb, s1buf, rmax, rsum, dww, wprbuf);
    cout_kernel<<<dim3(256, 1, 1), 256, 0, stream>>>(vcb, wprbuf, dwb, outs);

    // --- LN2 ---
    ln_kernel<<<dim3(2048, 1, 1), 256, 0, stream>>>(
        tgt1, nullptr, nullptr, outs, n2g, n2b, tgt2, tgt2b);

    // --- FFN ---
    gemm_nt<64, 128><<<dim3(512, 1, 1), 256, 0, stream>>>(
        tgt2b, w_l1, nullptr, ff1b, l1b,
        nullptr, nullptr, nullptr, nullptr,
        32, 16,
        1024, 1024, 1024, 2048,
        0, 0, 0, 0, 0, 0, 1, BIGZ, BIGN, 1.f, 2, 2);

    gemm_nt<64, 128><<<dim3(256, 1, 1), 256, 0, stream>>>(
        ff1b, w_l2, nullptr, ff2b, l2b,
        nullptr, nullptr, nullptr, nullptr,
        32, 8,
        2048, 2048, 2048, 1024,
        0, 0, 0, 0, 0, 0, 1, BIGZ, BIGN, 1.f, 1, 1);

    // --- LN3 -> d_out ---
    ln_kernel<<<dim3(2048, 1, 1), 256, 0, stream>>>(
        nullptr, ff2b, tgt2, nullptr, n3g, n3b, (float*)d_out, nullptr);
}